// Round 4
// baseline (1115.384 us; speedup 1.0000x reference)
//
#include <hip/hip_runtime.h>
#include <math.h>

// Problem constants: B=4, NF=64, H=W=128, K=9
// d_in order: nbr, ref, w1, b1, w2, b2, w3, b3, w_off, b_off, w_dcn, b_dcn
// d_out: feat [4,64,128,128] | offset [4,18,128,128] | mask [4,9,128,128]

typedef short bf8 __attribute__((ext_vector_type(8)));   // 8 bf16 (4 VGPRs)
typedef float f4  __attribute__((ext_vector_type(4)));   // 4 fp32 acc

__device__ __forceinline__ short f2bf(float f) {
  union { float f; unsigned u; } x{f};
  unsigned u = x.u;
  u += 0x7FFFu + ((u >> 16) & 1u);   // RNE
  return (short)(u >> 16);
}
__device__ __forceinline__ float bf2f(short h) {
  union { unsigned u; float f; } x;
  x.u = ((unsigned)(unsigned short)h) << 16;
  return x.f;
}

// ---------------- fp32 weight transpose (conv_off, dcn): w[oc][c][k] -> wT[(c*9+k)*OC + oc]
__global__ void wtrans_kernel(const float* __restrict__ in, float* __restrict__ out,
                              int OC, int IC) {
  int i = blockIdx.x * 256 + threadIdx.x;
  int total = OC * IC * 9;
  if (i >= total) return;
  int ic9 = IC * 9;
  int oc = i / ic9;
  int r = i - oc * ic9;
  int c = r / 9;
  int k = r - c * 9;
  out[(c * 9 + k) * OC + oc] = in[i];
}

// ---------------- bf16 hi/lo weight prep: w[oc][ic][tap] -> wA{h,l}[(tap*64+oc)*IC + ic]
__global__ void wprep_kernel(const float* __restrict__ in, short* __restrict__ out_h,
                             short* __restrict__ out_l, int IC) {
  int i = blockIdx.x * 256 + threadIdx.x;
  int total = 64 * IC * 9;
  if (i >= total) return;
  int oc = i / (IC * 9);
  int r = i - oc * IC * 9;
  int ic = r / 9;
  int tap = r - ic * 9;
  float f = in[i];
  short h = f2bf(f);
  short l = f2bf(f - bf2f(h));
  out_h[(tap * 64 + oc) * IC + ic] = h;
  out_l[(tap * 64 + oc) * IC + ic] = l;
}

// ---------------- NCHW -> NHWC transpose: (B,64,128,128) -> (B,128,128,64)
__global__ __launch_bounds__(256) void transpose_nhwc_kernel(const float* __restrict__ in,
                                                             float* __restrict__ out) {
  __shared__ float t[64 * 129];
  int bz = blockIdx.x;            // b*128 + y
  int b = bz >> 7, y = bz & 127;
  int tid = threadIdx.x;
  for (int l = tid; l < 8192; l += 256) {
    int c = l >> 7, x = l & 127;
    t[c * 129 + x] = in[(((b << 6) + c) << 14) + (y << 7) + x];
  }
  __syncthreads();
  for (int l = tid; l < 8192; l += 256) {
    int x = l >> 6, c = l & 63;
    out[(((((b << 7) + y) << 7) + x) << 6) + c] = t[c * 129 + x];
  }
}

// ---------------- MFMA conv3x3 + bias + lrelu, split-precision bf16 (hi/lo).
// acc = x_hi*w_hi + x_hi*w_lo + x_lo*w_hi  (fp32-equivalent to ~2^-18 rel).
// Block = one image row y (128 px), 4 waves, wave tile M=64 x N=32.
// X LDS tile: [3 rows][130 cols][72 c-pad] bf16 (one pass: hi or lo of a 64-ch chunk).
// wA layout: [(tap*64+oc)*IC + ic] bf16.
// mfma_f32_16x16x32_bf16 fragments (lane L, lm=L&15, lq=L>>4):
//   a[j] = A[m=lm][k=lq*8+j]   b[j] = B[k=lq*8+j][n=lm]   d[r]=D[row=lq*4+r][col=lm]
template <int IC, bool CONCAT>
__global__ __launch_bounds__(256, 2) void conv3x3_mfma_kernel(
    const float* __restrict__ in0, const float* __restrict__ in1,
    const short* __restrict__ wAh, const short* __restrict__ wAl,
    const float* __restrict__ bias, float* __restrict__ out) {
  __shared__ short Xs[3 * 130 * 72];
  int tid = threadIdx.x;
  int wv = tid >> 6, L = tid & 63;
  int lm = L & 15, lq = L >> 4;
  int y = blockIdx.x;
  int b = blockIdx.y;

  f4 acc[4][2];
#pragma unroll
  for (int i = 0; i < 4; ++i)
#pragma unroll
    for (int j = 0; j < 2; ++j) acc[i][j] = (f4)0.f;

  constexpr int NCH = IC / 64;
  for (int ch = 0; ch < NCH; ++ch) {
    const float* src = (CONCAT && ch == 1) ? in1 : in0;
    int cbase = ch * 64;
    for (int pass = 0; pass < 2; ++pass) {
      __syncthreads();
      // stage 64 ch x 3 rows x 130 px; pass0: bf16(x), pass1: bf16(x - bf16(x))
      for (int l = tid; l < 3120; l += 256) {
        int c8 = l / 390;            // 0..7  (8 channels each)
        int rem = l - c8 * 390;
        int row = rem / 130;         // 0..2
        int col = rem - row * 130;   // 0..129
        int px = col - 1;
        int gy = y + row - 1;
        bool ok = ((unsigned)gy < 128u) && ((unsigned)px < 128u);
        const float* gp = src + ((((size_t)(b << 6) + c8 * 8) << 14)) + (gy << 7) + px;
        bf8 v;
#pragma unroll
        for (int j = 0; j < 8; ++j) {
          float f = ok ? gp[(size_t)j << 14] : 0.f;
          short h = f2bf(f);
          v[j] = (pass == 0) ? h : f2bf(f - bf2f(h));
        }
        *(bf8*)&Xs[(row * 130 + col) * 72 + c8 * 8] = v;
      }
      __syncthreads();
#pragma unroll
      for (int tap = 0; tap < 9; ++tap) {
        const int row = tap / 3, kw = tap % 3;
#pragma unroll
        for (int ks = 0; ks < 2; ++ks) {
          size_t aoff = (size_t)(tap * 64 + lm) * IC + cbase + ks * 32 + lq * 8;
          const short* aph = wAh + aoff;
          bf8 a0 = *(const bf8*)(aph);
          bf8 a1 = *(const bf8*)(aph + 16 * IC);
          bf8 a2 = *(const bf8*)(aph + 32 * IC);
          bf8 a3 = *(const bf8*)(aph + 48 * IC);
          bf8 a0l, a1l, a2l, a3l;
          if (pass == 0) {
            const short* apl = wAl + aoff;
            a0l = *(const bf8*)(apl);
            a1l = *(const bf8*)(apl + 16 * IC);
            a2l = *(const bf8*)(apl + 32 * IC);
            a3l = *(const bf8*)(apl + 48 * IC);
          }
#pragma unroll
          for (int nt = 0; nt < 2; ++nt) {
            int col = wv * 32 + nt * 16 + lm + kw;
            bf8 bv = *(const bf8*)(&Xs[(row * 130 + col) * 72 + ks * 32 + lq * 8]);
            acc[0][nt] = __builtin_amdgcn_mfma_f32_16x16x32_bf16(a0, bv, acc[0][nt], 0, 0, 0);
            acc[1][nt] = __builtin_amdgcn_mfma_f32_16x16x32_bf16(a1, bv, acc[1][nt], 0, 0, 0);
            acc[2][nt] = __builtin_amdgcn_mfma_f32_16x16x32_bf16(a2, bv, acc[2][nt], 0, 0, 0);
            acc[3][nt] = __builtin_amdgcn_mfma_f32_16x16x32_bf16(a3, bv, acc[3][nt], 0, 0, 0);
            if (pass == 0) {
              acc[0][nt] = __builtin_amdgcn_mfma_f32_16x16x32_bf16(a0l, bv, acc[0][nt], 0, 0, 0);
              acc[1][nt] = __builtin_amdgcn_mfma_f32_16x16x32_bf16(a1l, bv, acc[1][nt], 0, 0, 0);
              acc[2][nt] = __builtin_amdgcn_mfma_f32_16x16x32_bf16(a2l, bv, acc[2][nt], 0, 0, 0);
              acc[3][nt] = __builtin_amdgcn_mfma_f32_16x16x32_bf16(a3l, bv, acc[3][nt], 0, 0, 0);
            }
          }
        }
      }
    }
  }
  // epilogue: bias + lrelu, store fp32 NCHW
#pragma unroll
  for (int mt = 0; mt < 4; ++mt)
#pragma unroll
    for (int nt = 0; nt < 2; ++nt) {
      int px = wv * 32 + nt * 16 + lm;
#pragma unroll
      for (int r = 0; r < 4; ++r) {
        int oc = mt * 16 + lq * 4 + r;
        float v = acc[mt][nt][r] + bias[oc];
        v = (v >= 0.f) ? v : 0.1f * v;
        out[(((b << 6) + oc) << 14) + (y << 7) + px] = v;
      }
    }
}

// ---------------- offset/mask conv: 64 -> 27 ch, fused 15*tanh / sigmoid.
// wT layout [c][k][27].
__global__ __launch_bounds__(256) void conv_off_kernel(
    const float* __restrict__ in0, const float* __restrict__ wT,
    const float* __restrict__ bias, float* __restrict__ off_out,
    float* __restrict__ mask_out) {
  constexpr int CC = 4;
  __shared__ float s_in[CC * 340];
  int tid = threadIdx.x;
  int tx = tid & 31, ty = tid >> 5;
  int w0 = blockIdx.x * 32, h0 = blockIdx.y * 8;
  int b = blockIdx.z;
  int h = h0 + ty, w = w0 + tx;

  float acc[27];
#pragma unroll
  for (int i = 0; i < 27; ++i) acc[i] = 0.f;

  for (int c0 = 0; c0 < 64; c0 += CC) {
    __syncthreads();
    for (int l = tid; l < CC * 340; l += 256) {
      int cc = l / 340;
      int rem = l - cc * 340;
      int r = rem / 34;
      int col = rem - r * 34;
      int gh = h0 - 1 + r;
      int gw = w0 - 1 + col;
      int c = c0 + cc;
      float val = 0.f;
      if ((unsigned)gh < 128u && (unsigned)gw < 128u)
        val = in0[(((b << 6) + c) << 14) + (gh << 7) + gw];
      s_in[l] = val;
    }
    __syncthreads();
#pragma unroll
    for (int cc = 0; cc < CC; ++cc) {
      int base = cc * 340 + ty * 34 + tx;
      float vv[9];
      vv[0] = s_in[base];      vv[1] = s_in[base + 1];  vv[2] = s_in[base + 2];
      vv[3] = s_in[base + 34]; vv[4] = s_in[base + 35]; vv[5] = s_in[base + 36];
      vv[6] = s_in[base + 68]; vv[7] = s_in[base + 69]; vv[8] = s_in[base + 70];
      const float* wr = wT + (c0 + cc) * 243;  // (c*9+k)*27
#pragma unroll
      for (int k = 0; k < 9; ++k) {
        const float* wk = wr + k * 27;
        float vk = vv[k];
#pragma unroll
        for (int oc = 0; oc < 27; ++oc)
          acc[oc] = fmaf(vk, wk[oc], acc[oc]);
      }
    }
  }
  int hw = (h << 7) + w;
#pragma unroll
  for (int oc = 0; oc < 27; ++oc) {
    float v = acc[oc] + bias[oc];
    if (oc < 18) {
      off_out[((b * 18 + oc) << 14) + hw] = 15.f * tanhf(v);
    } else {
      mask_out[((b * 9 + (oc - 18)) << 14) + hw] = 1.f / (1.f + expf(-v));
    }
  }
}

// ---------------- modulated deformable conv + bias + lrelu.
// xT is NHWC (B,128,128,64); wT layout [c][k][64] -> element (c*9+k)*64+oc.
__global__ __launch_bounds__(256) void dcn_lrelu_kernel(
    const float* __restrict__ xT, const float* __restrict__ off,
    const float* __restrict__ msk, const float* __restrict__ wT,
    const float* __restrict__ bias, float* __restrict__ out) {
  int tid = threadIdx.x;
  int tx = tid & 31, ty = tid >> 5;
  int w = blockIdx.x * 32 + tx;
  int h = blockIdx.y * 8 + ty;
  int b = blockIdx.z;
  int hw = (h << 7) + w;

  float acc[64];
#pragma unroll
  for (int i = 0; i < 64; ++i) acc[i] = 0.f;

#pragma unroll
  for (int k = 0; k < 9; ++k) {
    int kr = k / 3;
    int ki = kr - 1;
    int kj = k - kr * 3 - 1;
    float oy = off[((b * 18 + 2 * k) << 14) + hw];
    float ox = off[((b * 18 + 2 * k + 1) << 14) + hw];
    float m = msk[((b * 9 + k) << 14) + hw];
    float py = (float)(h + ki) + oy;
    float px = (float)(w + kj) + ox;
    float fy = floorf(py), fx = floorf(px);
    float wy = py - fy, wx = px - fx;
    int y0 = (int)fy, x0 = (int)fx;
    int y1 = y0 + 1, x1 = x0 + 1;
    float vy0 = ((unsigned)y0 < 128u) ? 1.f : 0.f;
    float vy1 = ((unsigned)y1 < 128u) ? 1.f : 0.f;
    float vx0 = ((unsigned)x0 < 128u) ? 1.f : 0.f;
    float vx1 = ((unsigned)x1 < 128u) ? 1.f : 0.f;
    float ey = 1.f - wy, ex = 1.f - wx;
    float w00 = ey * ex * m * vy0 * vx0;
    float w01 = ey * wx * m * vy0 * vx1;
    float w10 = wy * ex * m * vy1 * vx0;
    float w11 = wy * wx * m * vy1 * vx1;
    int y0c = min(max(y0, 0), 127), y1c = min(max(y1, 0), 127);
    int x0c = min(max(x0, 0), 127), x1c = min(max(x1, 0), 127);
    const float4* p00 = (const float4*)(xT + (size_t)((((b << 7) + y0c) << 7) + x0c) * 64);
    const float4* p01 = (const float4*)(xT + (size_t)((((b << 7) + y0c) << 7) + x1c) * 64);
    const float4* p10 = (const float4*)(xT + (size_t)((((b << 7) + y1c) << 7) + x0c) * 64);
    const float4* p11 = (const float4*)(xT + (size_t)((((b << 7) + y1c) << 7) + x1c) * 64);
    const float* wkb = wT + k * 64;
    for (int c4 = 0; c4 < 16; ++c4) {
      float4 a0 = p00[c4], a1 = p01[c4], a2 = p10[c4], a3 = p11[c4];
      float s0 = fmaf(w11, a3.x, fmaf(w10, a2.x, fmaf(w01, a1.x, w00 * a0.x)));
      float s1 = fmaf(w11, a3.y, fmaf(w10, a2.y, fmaf(w01, a1.y, w00 * a0.y)));
      float s2 = fmaf(w11, a3.z, fmaf(w10, a2.z, fmaf(w01, a1.z, w00 * a0.z)));
      float s3 = fmaf(w11, a3.w, fmaf(w10, a2.w, fmaf(w01, a1.w, w00 * a0.w)));
      const float* wk = wkb + c4 * 2304;  // c=4*c4, rows j at +576*j
#pragma unroll
      for (int oc = 0; oc < 64; ++oc) {
        float t = fmaf(s0, wk[oc], acc[oc]);
        t = fmaf(s1, wk[576 + oc], t);
        t = fmaf(s2, wk[1152 + oc], t);
        acc[oc] = fmaf(s3, wk[1728 + oc], t);
      }
    }
  }
#pragma unroll
  for (int oc = 0; oc < 64; ++oc) {
    float v = acc[oc] + bias[oc];
    v = (v >= 0.f) ? v : 0.1f * v;
    out[(((b << 6) + oc) << 14) + hw] = v;
  }
}

extern "C" void kernel_launch(void* const* d_in, const int* in_sizes, int n_in,
                              void* d_out, int out_size, void* d_ws, size_t ws_size,
                              hipStream_t stream) {
  const float* nbr   = (const float*)d_in[0];
  const float* refp  = (const float*)d_in[1];
  const float* w1    = (const float*)d_in[2];
  const float* b1    = (const float*)d_in[3];
  const float* w2    = (const float*)d_in[4];
  const float* b2    = (const float*)d_in[5];
  const float* w3    = (const float*)d_in[6];
  const float* b3    = (const float*)d_in[7];
  const float* w_off = (const float*)d_in[8];
  const float* b_off = (const float*)d_in[9];
  const float* w_dcn = (const float*)d_in[10];
  const float* b_dcn = (const float*)d_in[11];

  float* outp = (float*)d_out;
  float* feat = outp;                       // 4*64*16384 = 4194304
  float* offp = outp + 4194304;             // 4*18*16384 = 1179648
  float* mskp = outp + 4194304 + 1179648;   // 4*9*16384  = 589824

  char* ws = (char*)d_ws;
  float* buf0  = (float*)ws;                          // 16 MB ping buffer
  char* p = ws + ((size_t)16u << 20);
  float* wToff = (float*)p;  p += (size_t)15552 * 4;  // fp32 [c][k][27]
  float* wTdcn = (float*)p;  p += (size_t)36864 * 4;  // fp32 [c][k][64]
  short* wA1h  = (short*)p;  p += (size_t)73728 * 2;  // bf16 hi [tap][oc][128]
  short* wA1l  = (short*)p;  p += (size_t)73728 * 2;  // bf16 lo
  short* wA2h  = (short*)p;  p += (size_t)36864 * 2;
  short* wA2l  = (short*)p;  p += (size_t)36864 * 2;
  short* wA3h  = (short*)p;  p += (size_t)36864 * 2;
  short* wA3l  = (short*)p;

  wtrans_kernel<<<dim3((15552 + 255) / 256), 256, 0, stream>>>(w_off, wToff, 27, 64);
  wtrans_kernel<<<dim3((36864 + 255) / 256), 256, 0, stream>>>(w_dcn, wTdcn, 64, 64);
  wprep_kernel<<<dim3((73728 + 255) / 256), 256, 0, stream>>>(w1, wA1h, wA1l, 128);
  wprep_kernel<<<dim3((36864 + 255) / 256), 256, 0, stream>>>(w2, wA2h, wA2l, 64);
  wprep_kernel<<<dim3((36864 + 255) / 256), 256, 0, stream>>>(w3, wA3h, wA3l, 64);

  // conv1: concat(nbr,ref) 128ch -> 64ch, lrelu, into buf0  (MFMA split-precision)
  conv3x3_mfma_kernel<128, true><<<dim3(128, 4), 256, 0, stream>>>(nbr, refp, wA1h, wA1l, b1, buf0);
  // conv2: buf0 -> feat region (pong; overwritten later by DCN)
  conv3x3_mfma_kernel<64, false><<<dim3(128, 4), 256, 0, stream>>>(buf0, nullptr, wA2h, wA2l, b2, feat);
  // conv3: feat -> buf0
  conv3x3_mfma_kernel<64, false><<<dim3(128, 4), 256, 0, stream>>>(feat, nullptr, wA3h, wA3l, b3, buf0);
  // conv_off: buf0 -> offset/mask output regions (fused 15*tanh / sigmoid)
  conv_off_kernel<<<dim3(4, 16, 4), 256, 0, stream>>>(buf0, wToff, b_off, offp, mskp);
  // transpose nbr -> NHWC into buf0 (conv outputs no longer needed there)
  transpose_nhwc_kernel<<<dim3(512), 256, 0, stream>>>(nbr, buf0);
  // DCN: sample buf0 (NHWC) at offsets, modulate, matmul, +bias, lrelu -> feat
  dcn_lrelu_kernel<<<dim3(4, 16, 4), 256, 0, stream>>>(buf0, offp, mskp, wTdcn, b_dcn, feat);
}

// Round 5
// 629.220 us; speedup vs baseline: 1.7726x; 1.7726x over previous
//
#include <hip/hip_runtime.h>
#include <math.h>

// Problem constants: B=4, NF=64, H=W=128, K=9
// d_in order: nbr, ref, w1, b1, w2, b2, w3, b3, w_off, b_off, w_dcn, b_dcn
// d_out: feat [4,64,128,128] | offset [4,18,128,128] | mask [4,9,128,128]

typedef _Float16 h8 __attribute__((ext_vector_type(8)));  // 8 f16 (4 VGPRs)
typedef float f4 __attribute__((ext_vector_type(4)));     // 4 fp32 acc

// ---------------- fp32 weight transpose (conv_off, dcn): w[oc][c][k] -> wT[(c*9+k)*OC + oc]
__global__ void wtrans_kernel(const float* __restrict__ in, float* __restrict__ out,
                              int OC, int IC) {
  int i = blockIdx.x * 256 + threadIdx.x;
  int total = OC * IC * 9;
  if (i >= total) return;
  int ic9 = IC * 9;
  int oc = i / ic9;
  int r = i - oc * ic9;
  int c = r / 9;
  int k = r - c * 9;
  out[(c * 9 + k) * OC + oc] = in[i];
}

// ---------------- f16 weight prep: w[oc][ic][tap] -> wF[((tap*NCH+ch)*64+oc)*32 + icw]
// (tap,chunk) slice = 64 oc x 32 ch = 4 KB contiguous.
__global__ void wprep_f16_kernel(const float* __restrict__ in, _Float16* __restrict__ out,
                                 int NCH) {
  int i = blockIdx.x * 256 + threadIdx.x;
  int IC = NCH * 32;
  if (i >= 64 * IC * 9) return;
  int icw = i & 31;
  int t1 = i >> 5;
  int oc = t1 & 63;
  int t2 = t1 >> 6;          // tap*NCH + ch
  int ch = t2 % NCH;
  int tap = t2 / NCH;
  int ic = ch * 32 + icw;
  out[i] = (_Float16)in[(oc * IC + ic) * 9 + tap];
}

// ---------------- fp32 NCHW -> zero-padded NHWC f16 [B][130][130][CH] (uint-packed pairs)
template <int CH, bool CONCAT>
__global__ __launch_bounds__(256) void prep_nhwc_f16_kernel(
    const float* __restrict__ src0, const float* __restrict__ src1,
    unsigned* __restrict__ dst) {
  __shared__ float t[CH * 129];
  int bz = blockIdx.x;               // b*130 + py
  int b = bz / 130, py = bz - b * 130;
  int tid = threadIdx.x;
  bool interior = (py >= 1 && py <= 128);
  if (interior) {
    int gy = py - 1;
    for (int l = tid; l < CH * 128; l += 256) {
      int c = l >> 7, gx = l & 127;
      const float* sp = src0;
      int cl = c;
      if (CONCAT && c >= 64) { sp = src1; cl = c - 64; }
      t[c * 129 + gx] = sp[(((size_t)b * 64 + cl) << 14) + (gy << 7) + gx];
    }
  }
  __syncthreads();
  constexpr int CH2 = CH / 2;
  for (int l = tid; l < 130 * CH2; l += 256) {
    int px = l / CH2, c2 = l - px * CH2;
    unsigned v = 0u;
    if (interior && px >= 1 && px <= 128) {
      int gx = px - 1;
      union { _Float16 h[2]; unsigned u; } pk;
      pk.h[0] = (_Float16)t[(2 * c2) * 129 + gx];
      pk.h[1] = (_Float16)t[(2 * c2 + 1) * 129 + gx];
      v = pk.u;
    }
    dst[(size_t)bz * (130 * CH2) + l] = v;
  }
}

// ---------------- NCHW -> NHWC fp32 transpose (for DCN): (B,64,128,128) -> (B,128,128,64)
__global__ __launch_bounds__(256) void transpose_nhwc_kernel(const float* __restrict__ in,
                                                             float* __restrict__ out) {
  __shared__ float t[64 * 129];
  int bz = blockIdx.x;            // b*128 + y
  int b = bz >> 7, y = bz & 127;
  int tid = threadIdx.x;
  for (int l = tid; l < 8192; l += 256) {
    int c = l >> 7, x = l & 127;
    t[c * 129 + x] = in[(((b << 6) + c) << 14) + (y << 7) + x];
  }
  __syncthreads();
  for (int l = tid; l < 8192; l += 256) {
    int x = l >> 6, c = l & 63;
    out[(((((b << 7) + y) << 7) + x) << 6) + c] = t[c * 129 + x];
  }
}

// ---------------- f16 MFMA conv3x3 + bias + lrelu. No LDS, no barriers.
// X: padded NHWC f16 [B][130][130][CH]; W: f16 slices [(tap*NCH+c)*64+oc][32].
// Block = one row y (swizzled for XCD L2 strips), 4 waves x 32 px; wave M=64 N=32.
// mfma_f32_16x16x32_f16 (lane L, lm=L&15, lq=L>>4):
//   a[j]=A[m=lm][k=lq*8+j]  b[j]=B[k=lq*8+j][n=lm]  d[r]=D[row=lq*4+r][col=lm]
template <int CH>
__global__ __launch_bounds__(256, 4) void conv3x3_f16_kernel(
    const _Float16* __restrict__ X, const _Float16* __restrict__ W,
    const float* __restrict__ bias, float* __restrict__ out) {
  constexpr int NCH = CH / 32;
  int tid = threadIdx.x;
  int wv = tid >> 6, L = tid & 63;
  int lm = L & 15, lq = L >> 4;
  int bid = blockIdx.x;                 // 512 = 8 xcd * 16 ystrip * 4 b
  int xcd = bid & 7, j = bid >> 3;
  int y = (xcd << 4) | (j & 15);
  int b = j >> 4;
  int px0 = wv * 32;

  f4 acc[4][2];
#pragma unroll
  for (int i = 0; i < 4; ++i)
#pragma unroll
    for (int n = 0; n < 2; ++n) acc[i][n] = (f4)0.f;

  for (int c = 0; c < NCH; ++c) {
#pragma unroll
    for (int tap = 0; tap < 9; ++tap) {
      const int dy = tap / 3 - 1, dx = tap % 3 - 1;
      const _Float16* xb = X + ((size_t)((b * 130 + (y + 1 + dy)) * 130) + (1 + dx) + px0) * CH
                             + c * 32 + lq * 8;
      h8 b0 = *(const h8*)(xb + lm * CH);
      h8 b1 = *(const h8*)(xb + (16 + lm) * CH);
      const _Float16* wp = W + (size_t)((tap * NCH + c) * 64) * 32 + lm * 32 + lq * 8;
      h8 a0 = *(const h8*)(wp);
      h8 a1 = *(const h8*)(wp + 512);
      h8 a2 = *(const h8*)(wp + 1024);
      h8 a3 = *(const h8*)(wp + 1536);
      acc[0][0] = __builtin_amdgcn_mfma_f32_16x16x32_f16(a0, b0, acc[0][0], 0, 0, 0);
      acc[1][0] = __builtin_amdgcn_mfma_f32_16x16x32_f16(a1, b0, acc[1][0], 0, 0, 0);
      acc[2][0] = __builtin_amdgcn_mfma_f32_16x16x32_f16(a2, b0, acc[2][0], 0, 0, 0);
      acc[3][0] = __builtin_amdgcn_mfma_f32_16x16x32_f16(a3, b0, acc[3][0], 0, 0, 0);
      acc[0][1] = __builtin_amdgcn_mfma_f32_16x16x32_f16(a0, b1, acc[0][1], 0, 0, 0);
      acc[1][1] = __builtin_amdgcn_mfma_f32_16x16x32_f16(a1, b1, acc[1][1], 0, 0, 0);
      acc[2][1] = __builtin_amdgcn_mfma_f32_16x16x32_f16(a2, b1, acc[2][1], 0, 0, 0);
      acc[3][1] = __builtin_amdgcn_mfma_f32_16x16x32_f16(a3, b1, acc[3][1], 0, 0, 0);
    }
  }
  // epilogue: bias + lrelu, fp32 NCHW
#pragma unroll
  for (int mt = 0; mt < 4; ++mt)
#pragma unroll
    for (int nt = 0; nt < 2; ++nt) {
      int px = px0 + nt * 16 + lm;
#pragma unroll
      for (int r = 0; r < 4; ++r) {
        int oc = mt * 16 + lq * 4 + r;
        float v = acc[mt][nt][r] + bias[oc];
        v = (v >= 0.f) ? v : 0.1f * v;
        out[(((b << 6) + oc) << 14) + (y << 7) + px] = v;
      }
    }
}

// ---------------- offset/mask conv: 64 -> 27 ch, fused 15*tanh / sigmoid. wT [c][k][27].
__global__ __launch_bounds__(256) void conv_off_kernel(
    const float* __restrict__ in0, const float* __restrict__ wT,
    const float* __restrict__ bias, float* __restrict__ off_out,
    float* __restrict__ mask_out) {
  constexpr int CC = 4;
  __shared__ float s_in[CC * 340];
  int tid = threadIdx.x;
  int tx = tid & 31, ty = tid >> 5;
  int w0 = blockIdx.x * 32, h0 = blockIdx.y * 8;
  int b = blockIdx.z;
  int h = h0 + ty, w = w0 + tx;

  float acc[27];
#pragma unroll
  for (int i = 0; i < 27; ++i) acc[i] = 0.f;

  for (int c0 = 0; c0 < 64; c0 += CC) {
    __syncthreads();
    for (int l = tid; l < CC * 340; l += 256) {
      int cc = l / 340;
      int rem = l - cc * 340;
      int r = rem / 34;
      int col = rem - r * 34;
      int gh = h0 - 1 + r;
      int gw = w0 - 1 + col;
      int c = c0 + cc;
      float val = 0.f;
      if ((unsigned)gh < 128u && (unsigned)gw < 128u)
        val = in0[(((b << 6) + c) << 14) + (gh << 7) + gw];
      s_in[l] = val;
    }
    __syncthreads();
#pragma unroll
    for (int cc = 0; cc < CC; ++cc) {
      int base = cc * 340 + ty * 34 + tx;
      float vv[9];
      vv[0] = s_in[base];      vv[1] = s_in[base + 1];  vv[2] = s_in[base + 2];
      vv[3] = s_in[base + 34]; vv[4] = s_in[base + 35]; vv[5] = s_in[base + 36];
      vv[6] = s_in[base + 68]; vv[7] = s_in[base + 69]; vv[8] = s_in[base + 70];
      const float* wr = wT + (c0 + cc) * 243;
#pragma unroll
      for (int k = 0; k < 9; ++k) {
        const float* wk = wr + k * 27;
        float vk = vv[k];
#pragma unroll
        for (int oc = 0; oc < 27; ++oc)
          acc[oc] = fmaf(vk, wk[oc], acc[oc]);
      }
    }
  }
  int hw = (h << 7) + w;
#pragma unroll
  for (int oc = 0; oc < 27; ++oc) {
    float v = acc[oc] + bias[oc];
    if (oc < 18) {
      off_out[((b * 18 + oc) << 14) + hw] = 15.f * tanhf(v);
    } else {
      mask_out[((b * 9 + (oc - 18)) << 14) + hw] = 1.f / (1.f + expf(-v));
    }
  }
}

// ---------------- modulated deformable conv + bias + lrelu.
// xT NHWC (B,128,128,64) fp32; wT [c][k][64].
__global__ __launch_bounds__(256) void dcn_lrelu_kernel(
    const float* __restrict__ xT, const float* __restrict__ off,
    const float* __restrict__ msk, const float* __restrict__ wT,
    const float* __restrict__ bias, float* __restrict__ out) {
  int tid = threadIdx.x;
  int tx = tid & 31, ty = tid >> 5;
  int w = blockIdx.x * 32 + tx;
  int h = blockIdx.y * 8 + ty;
  int b = blockIdx.z;
  int hw = (h << 7) + w;

  float acc[64];
#pragma unroll
  for (int i = 0; i < 64; ++i) acc[i] = 0.f;

#pragma unroll
  for (int k = 0; k < 9; ++k) {
    int kr = k / 3;
    int ki = kr - 1;
    int kj = k - kr * 3 - 1;
    float oy = off[((b * 18 + 2 * k) << 14) + hw];
    float ox = off[((b * 18 + 2 * k + 1) << 14) + hw];
    float m = msk[((b * 9 + k) << 14) + hw];
    float py = (float)(h + ki) + oy;
    float px = (float)(w + kj) + ox;
    float fy = floorf(py), fx = floorf(px);
    float wy = py - fy, wx = px - fx;
    int y0 = (int)fy, x0 = (int)fx;
    int y1 = y0 + 1, x1 = x0 + 1;
    float vy0 = ((unsigned)y0 < 128u) ? 1.f : 0.f;
    float vy1 = ((unsigned)y1 < 128u) ? 1.f : 0.f;
    float vx0 = ((unsigned)x0 < 128u) ? 1.f : 0.f;
    float vx1 = ((unsigned)x1 < 128u) ? 1.f : 0.f;
    float ey = 1.f - wy, ex = 1.f - wx;
    float w00 = ey * ex * m * vy0 * vx0;
    float w01 = ey * wx * m * vy0 * vx1;
    float w10 = wy * ex * m * vy1 * vx0;
    float w11 = wy * wx * m * vy1 * vx1;
    int y0c = min(max(y0, 0), 127), y1c = min(max(y1, 0), 127);
    int x0c = min(max(x0, 0), 127), x1c = min(max(x1, 0), 127);
    const float4* p00 = (const float4*)(xT + (size_t)((((b << 7) + y0c) << 7) + x0c) * 64);
    const float4* p01 = (const float4*)(xT + (size_t)((((b << 7) + y0c) << 7) + x1c) * 64);
    const float4* p10 = (const float4*)(xT + (size_t)((((b << 7) + y1c) << 7) + x0c) * 64);
    const float4* p11 = (const float4*)(xT + (size_t)((((b << 7) + y1c) << 7) + x1c) * 64);
    const float* wkb = wT + k * 64;
    for (int c4 = 0; c4 < 16; ++c4) {
      float4 a0 = p00[c4], a1 = p01[c4], a2 = p10[c4], a3 = p11[c4];
      float s0 = fmaf(w11, a3.x, fmaf(w10, a2.x, fmaf(w01, a1.x, w00 * a0.x)));
      float s1 = fmaf(w11, a3.y, fmaf(w10, a2.y, fmaf(w01, a1.y, w00 * a0.y)));
      float s2 = fmaf(w11, a3.z, fmaf(w10, a2.z, fmaf(w01, a1.z, w00 * a0.z)));
      float s3 = fmaf(w11, a3.w, fmaf(w10, a2.w, fmaf(w01, a1.w, w00 * a0.w)));
      const float* wk = wkb + c4 * 2304;
#pragma unroll
      for (int oc = 0; oc < 64; ++oc) {
        float t = fmaf(s0, wk[oc], acc[oc]);
        t = fmaf(s1, wk[576 + oc], t);
        t = fmaf(s2, wk[1152 + oc], t);
        acc[oc] = fmaf(s3, wk[1728 + oc], t);
      }
    }
  }
#pragma unroll
  for (int oc = 0; oc < 64; ++oc) {
    float v = acc[oc] + bias[oc];
    v = (v >= 0.f) ? v : 0.1f * v;
    out[(((b << 6) + oc) << 14) + hw] = v;
  }
}

extern "C" void kernel_launch(void* const* d_in, const int* in_sizes, int n_in,
                              void* d_out, int out_size, void* d_ws, size_t ws_size,
                              hipStream_t stream) {
  const float* nbr   = (const float*)d_in[0];
  const float* refp  = (const float*)d_in[1];
  const float* w1    = (const float*)d_in[2];
  const float* b1    = (const float*)d_in[3];
  const float* w2    = (const float*)d_in[4];
  const float* b2    = (const float*)d_in[5];
  const float* w3    = (const float*)d_in[6];
  const float* b3    = (const float*)d_in[7];
  const float* w_off = (const float*)d_in[8];
  const float* b_off = (const float*)d_in[9];
  const float* w_dcn = (const float*)d_in[10];
  const float* b_dcn = (const float*)d_in[11];

  float* outp = (float*)d_out;
  float* feat = outp;                       // 4*64*16384 = 4194304
  float* offp = outp + 4194304;             // 4*18*16384 = 1179648
  float* mskp = outp + 4194304 + 1179648;   // 4*9*16384  = 589824

  char* ws = (char*)d_ws;
  // buf0: fp32 NCHW scratch (16 MB)
  float* buf0 = (float*)ws;
  // bufA region (17.31 MB), time-shared:
  //   phase 1: padded NHWC f16 [4][130][130][128]  (conv1 input)
  //   phase 2: padded NHWC f16 [4][130][130][64]   (conv2/conv3 inputs)
  //   phase 3: NHWC fp32 [4][128][128][64]         (DCN input)
  char* bufA = ws + ((size_t)16u << 20);
  _Float16* nhwc128 = (_Float16*)bufA;              // 17,305,600 B
  _Float16* nhwc64  = (_Float16*)bufA;              // 8,652,800 B (after conv1 done)
  float*    xT_dcn  = (float*)bufA;                 // 16,777,216 B (after convs done)
  char* p = bufA + (size_t)17506304;                // 17.31 MB rounded up to 256
  float*    wToff = (float*)p;  p += (size_t)15552 * 4;
  float*    wTdcn = (float*)p;  p += (size_t)36864 * 4;
  _Float16* wF1   = (_Float16*)p;  p += (size_t)73728 * 2;   // [tap][4ch][64oc][32]
  _Float16* wF2   = (_Float16*)p;  p += (size_t)36864 * 2;
  _Float16* wF3   = (_Float16*)p;

  wtrans_kernel<<<dim3((15552 + 255) / 256), 256, 0, stream>>>(w_off, wToff, 27, 64);
  wtrans_kernel<<<dim3((36864 + 255) / 256), 256, 0, stream>>>(w_dcn, wTdcn, 64, 64);
  wprep_f16_kernel<<<dim3((73728 + 255) / 256), 256, 0, stream>>>(w1, wF1, 4);
  wprep_f16_kernel<<<dim3((36864 + 255) / 256), 256, 0, stream>>>(w2, wF2, 2);
  wprep_f16_kernel<<<dim3((36864 + 255) / 256), 256, 0, stream>>>(w3, wF3, 2);

  // conv1: concat(nbr,ref) -> buf0 (fp32 NCHW)
  prep_nhwc_f16_kernel<128, true><<<dim3(520), 256, 0, stream>>>(nbr, refp, (unsigned*)nhwc128);
  conv3x3_f16_kernel<128><<<dim3(512), 256, 0, stream>>>(nhwc128, wF1, b1, buf0);
  // conv2: buf0 -> feat (pong; overwritten later by DCN)
  prep_nhwc_f16_kernel<64, false><<<dim3(520), 256, 0, stream>>>(buf0, nullptr, (unsigned*)nhwc64);
  conv3x3_f16_kernel<64><<<dim3(512), 256, 0, stream>>>(nhwc64, wF2, b2, feat);
  // conv3: feat -> buf0
  prep_nhwc_f16_kernel<64, false><<<dim3(520), 256, 0, stream>>>(feat, nullptr, (unsigned*)nhwc64);
  conv3x3_f16_kernel<64><<<dim3(512), 256, 0, stream>>>(nhwc64, wF3, b3, buf0);
  // conv_off: buf0 -> offset/mask (fused 15*tanh / sigmoid)
  conv_off_kernel<<<dim3(4, 16, 4), 256, 0, stream>>>(buf0, wToff, b_off, offp, mskp);
  // DCN: nbr -> NHWC fp32, then sample/modulate/matmul -> feat
  transpose_nhwc_kernel<<<dim3(512), 256, 0, stream>>>(nbr, xT_dcn);
  dcn_lrelu_kernel<<<dim3(4, 16, 4), 256, 0, stream>>>(xT_dcn, offp, mskp, wTdcn, b_dcn, feat);
}

// Round 6
// 361.726 us; speedup vs baseline: 3.0835x; 1.7395x over previous
//
#include <hip/hip_runtime.h>
#include <math.h>

// Problem constants: B=4, NF=64, H=W=128, K=9
// d_in order: nbr, ref, w1, b1, w2, b2, w3, b3, w_off, b_off, w_dcn, b_dcn
// d_out: feat [4,64,128,128] | offset [4,18,128,128] | mask [4,9,128,128]

typedef _Float16 h8 __attribute__((ext_vector_type(8)));  // 8 f16 (4 VGPRs)
typedef float f4 __attribute__((ext_vector_type(4)));     // 4 fp32 acc

// ---------------- f16 weight prep (convs): w[oc][ic][tap] -> wF[((tap*NCH+ch)*64+oc)*32+icw]
__global__ void wprep_f16_kernel(const float* __restrict__ in, _Float16* __restrict__ out,
                                 int NCH) {
  int i = blockIdx.x * 256 + threadIdx.x;
  int IC = NCH * 32;
  if (i >= 64 * IC * 9) return;
  int icw = i & 31;
  int t1 = i >> 5;
  int oc = t1 & 63;
  int t2 = t1 >> 6;          // tap*NCH + ch
  int ch = t2 % NCH;
  int tap = t2 / NCH;
  int ic = ch * 32 + icw;
  out[i] = (_Float16)in[(oc * IC + ic) * 9 + tap];
}

// ---------------- f16 weight prep (conv_off, OC 27 padded to 32): -> [((tap*2+ch)*32+oc)*32+icw]
__global__ void wprep_off_kernel(const float* __restrict__ in, _Float16* __restrict__ out) {
  int i = blockIdx.x * 256 + threadIdx.x;
  if (i >= 9 * 2 * 32 * 32) return;
  int icw = i & 31;
  int t1 = i >> 5;
  int oc = t1 & 31;
  int t2 = t1 >> 5;          // tap*2 + ch
  int ch = t2 & 1;
  int tap = t2 >> 1;
  int ic = ch * 32 + icw;
  float v = (oc < 27) ? in[(oc * 64 + ic) * 9 + tap] : 0.f;
  out[i] = (_Float16)v;
}

// ---------------- f16 weight prep (dcn): w[oc][c][tap] -> wD[oc*576 + tap*64 + c]
__global__ void wprep_dcn_kernel(const float* __restrict__ in, _Float16* __restrict__ out) {
  int i = blockIdx.x * 256 + threadIdx.x;
  if (i >= 64 * 576) return;
  int oc = i / 576;
  int r = i - oc * 576;
  int tap = r >> 6;
  int c = r & 63;
  out[i] = (_Float16)in[(oc * 64 + c) * 9 + tap];
}

// ---------------- fp32 NCHW -> zero-padded NHWC f16 [B][130][130][CH] (uint-packed pairs)
template <int CH, bool CONCAT>
__global__ __launch_bounds__(256) void prep_nhwc_f16_kernel(
    const float* __restrict__ src0, const float* __restrict__ src1,
    unsigned* __restrict__ dst) {
  __shared__ float t[CH * 129];
  int bz = blockIdx.x;               // b*130 + py
  int b = bz / 130, py = bz - b * 130;
  int tid = threadIdx.x;
  bool interior = (py >= 1 && py <= 128);
  if (interior) {
    int gy = py - 1;
    for (int l = tid; l < CH * 128; l += 256) {
      int c = l >> 7, gx = l & 127;
      const float* sp = src0;
      int cl = c;
      if (CONCAT && c >= 64) { sp = src1; cl = c - 64; }
      t[c * 129 + gx] = sp[(((size_t)b * 64 + cl) << 14) + (gy << 7) + gx];
    }
  }
  __syncthreads();
  constexpr int CH2 = CH / 2;
  for (int l = tid; l < 130 * CH2; l += 256) {
    int px = l / CH2, c2 = l - px * CH2;
    unsigned v = 0u;
    if (interior && px >= 1 && px <= 128) {
      int gx = px - 1;
      union { _Float16 h[2]; unsigned u; } pk;
      pk.h[0] = (_Float16)t[(2 * c2) * 129 + gx];
      pk.h[1] = (_Float16)t[(2 * c2 + 1) * 129 + gx];
      v = pk.u;
    }
    dst[(size_t)bz * (130 * CH2) + l] = v;
  }
}

// ---------------- fp32 NCHW -> NHWC f16 (unpadded, for DCN): (B,64,128,128)->(B,128,128,64)
__global__ __launch_bounds__(256) void transpose_nhwc_f16_kernel(const float* __restrict__ in,
                                                                 unsigned* __restrict__ out) {
  __shared__ float t[64 * 129];
  int bz = blockIdx.x;            // b*128 + y
  int b = bz >> 7, y = bz & 127;
  int tid = threadIdx.x;
  for (int l = tid; l < 8192; l += 256) {
    int c = l >> 7, x = l & 127;
    t[c * 129 + x] = in[(((b << 6) + c) << 14) + (y << 7) + x];
  }
  __syncthreads();
  for (int l = tid; l < 4096; l += 256) {
    int x = l >> 5, c2 = l & 31;
    union { _Float16 h[2]; unsigned u; } pk;
    pk.h[0] = (_Float16)t[(2 * c2) * 129 + x];
    pk.h[1] = (_Float16)t[(2 * c2 + 1) * 129 + x];
    out[(size_t)bz * 4096 + (size_t)x * 32 + c2] = pk.u;
  }
}

// ---------------- f16 MFMA conv3x3 + bias + lrelu. No LDS, no barriers.
// X: padded NHWC f16 [B][130][130][CH]; W: f16 slices [(tap*NCH+c)*64+oc][32].
// mfma_f32_16x16x32_f16 (lane L, lm=L&15, lq=L>>4):
//   a[j]=A[m=lm][k=lq*8+j]  b[j]=B[k=lq*8+j][n=lm]  d[r]=D[row=lq*4+r][col=lm]
template <int CH>
__global__ __launch_bounds__(256, 4) void conv3x3_f16_kernel(
    const _Float16* __restrict__ X, const _Float16* __restrict__ W,
    const float* __restrict__ bias, float* __restrict__ out) {
  constexpr int NCH = CH / 32;
  int tid = threadIdx.x;
  int wv = tid >> 6, L = tid & 63;
  int lm = L & 15, lq = L >> 4;
  int bid = blockIdx.x;                 // 512 = 8 xcd * 16 ystrip * 4 b
  int xcd = bid & 7, j = bid >> 3;
  int y = (xcd << 4) | (j & 15);
  int b = j >> 4;
  int px0 = wv * 32;

  f4 acc[4][2];
#pragma unroll
  for (int i = 0; i < 4; ++i)
#pragma unroll
    for (int n = 0; n < 2; ++n) acc[i][n] = (f4)0.f;

  for (int c = 0; c < NCH; ++c) {
#pragma unroll
    for (int tap = 0; tap < 9; ++tap) {
      const int dy = tap / 3 - 1, dx = tap % 3 - 1;
      const _Float16* xb = X + ((size_t)((b * 130 + (y + 1 + dy)) * 130) + (1 + dx) + px0) * CH
                             + c * 32 + lq * 8;
      h8 b0 = *(const h8*)(xb + lm * CH);
      h8 b1 = *(const h8*)(xb + (16 + lm) * CH);
      const _Float16* wp = W + (size_t)((tap * NCH + c) * 64) * 32 + lm * 32 + lq * 8;
      h8 a0 = *(const h8*)(wp);
      h8 a1 = *(const h8*)(wp + 512);
      h8 a2 = *(const h8*)(wp + 1024);
      h8 a3 = *(const h8*)(wp + 1536);
      acc[0][0] = __builtin_amdgcn_mfma_f32_16x16x32_f16(a0, b0, acc[0][0], 0, 0, 0);
      acc[1][0] = __builtin_amdgcn_mfma_f32_16x16x32_f16(a1, b0, acc[1][0], 0, 0, 0);
      acc[2][0] = __builtin_amdgcn_mfma_f32_16x16x32_f16(a2, b0, acc[2][0], 0, 0, 0);
      acc[3][0] = __builtin_amdgcn_mfma_f32_16x16x32_f16(a3, b0, acc[3][0], 0, 0, 0);
      acc[0][1] = __builtin_amdgcn_mfma_f32_16x16x32_f16(a0, b1, acc[0][1], 0, 0, 0);
      acc[1][1] = __builtin_amdgcn_mfma_f32_16x16x32_f16(a1, b1, acc[1][1], 0, 0, 0);
      acc[2][1] = __builtin_amdgcn_mfma_f32_16x16x32_f16(a2, b1, acc[2][1], 0, 0, 0);
      acc[3][1] = __builtin_amdgcn_mfma_f32_16x16x32_f16(a3, b1, acc[3][1], 0, 0, 0);
    }
  }
#pragma unroll
  for (int mt = 0; mt < 4; ++mt)
#pragma unroll
    for (int nt = 0; nt < 2; ++nt) {
      int px = px0 + nt * 16 + lm;
#pragma unroll
      for (int r = 0; r < 4; ++r) {
        int oc = mt * 16 + lq * 4 + r;
        float v = acc[mt][nt][r] + bias[oc];
        v = (v >= 0.f) ? v : 0.1f * v;
        out[(((b << 6) + oc) << 14) + (y << 7) + px] = v;
      }
    }
}

// ---------------- f16 MFMA conv_off: 64 -> 27(pad 32), fused 15*tanh / sigmoid.
// W: [(tap*2+c)*32+oc][32] f16 (oc>=27 zero).
__global__ __launch_bounds__(256, 4) void conv_off_f16_kernel(
    const _Float16* __restrict__ X, const _Float16* __restrict__ W,
    const float* __restrict__ bias, float* __restrict__ off_out,
    float* __restrict__ mask_out) {
  int tid = threadIdx.x;
  int wv = tid >> 6, L = tid & 63;
  int lm = L & 15, lq = L >> 4;
  int bid = blockIdx.x;
  int xcd = bid & 7, j = bid >> 3;
  int y = (xcd << 4) | (j & 15);
  int b = j >> 4;
  int px0 = wv * 32;

  f4 acc[2][2];
#pragma unroll
  for (int i = 0; i < 2; ++i)
#pragma unroll
    for (int n = 0; n < 2; ++n) acc[i][n] = (f4)0.f;

  for (int c = 0; c < 2; ++c) {
#pragma unroll
    for (int tap = 0; tap < 9; ++tap) {
      const int dy = tap / 3 - 1, dx = tap % 3 - 1;
      const _Float16* xb = X + ((size_t)((b * 130 + (y + 1 + dy)) * 130) + (1 + dx) + px0) * 64
                             + c * 32 + lq * 8;
      h8 b0 = *(const h8*)(xb + lm * 64);
      h8 b1 = *(const h8*)(xb + (16 + lm) * 64);
      const _Float16* wp = W + (size_t)((tap * 2 + c) * 32 + lm) * 32 + lq * 8;
      h8 a0 = *(const h8*)(wp);
      h8 a1 = *(const h8*)(wp + 512);
      acc[0][0] = __builtin_amdgcn_mfma_f32_16x16x32_f16(a0, b0, acc[0][0], 0, 0, 0);
      acc[1][0] = __builtin_amdgcn_mfma_f32_16x16x32_f16(a1, b0, acc[1][0], 0, 0, 0);
      acc[0][1] = __builtin_amdgcn_mfma_f32_16x16x32_f16(a0, b1, acc[0][1], 0, 0, 0);
      acc[1][1] = __builtin_amdgcn_mfma_f32_16x16x32_f16(a1, b1, acc[1][1], 0, 0, 0);
    }
  }
#pragma unroll
  for (int mt = 0; mt < 2; ++mt)
#pragma unroll
    for (int nt = 0; nt < 2; ++nt) {
      int px = px0 + nt * 16 + lm;
      int hw = (y << 7) + px;
#pragma unroll
      for (int r = 0; r < 4; ++r) {
        int oc = mt * 16 + lq * 4 + r;
        if (oc < 18) {
          float v = acc[mt][nt][r] + bias[oc];
          off_out[((b * 18 + oc) << 14) + hw] = 15.f * tanhf(v);
        } else if (oc < 27) {
          float v = acc[mt][nt][r] + bias[oc];
          mask_out[((b * 9 + (oc - 18)) << 14) + hw] = 1.f / (1.f + expf(-v));
        }
      }
    }
}

// ---------------- DCN: bilinear sample (f16) -> LDS -> MFMA matmul + bias + lrelu.
// xT: NHWC f16 (B,128,128,64); wD: f16 [oc][tap*64+c] (K=576); block = 64 px.
// Two K passes: taps 0-4 (K=320), taps 5-8 (K=256). LDS S[64 px][328 pad].
__global__ __launch_bounds__(256, 3) void dcn_mfma_kernel(
    const _Float16* __restrict__ xT, const float* __restrict__ off,
    const float* __restrict__ msk, const _Float16* __restrict__ wD,
    const float* __restrict__ bias, float* __restrict__ out) {
  __shared__ _Float16 S[64 * 328];
  int tid = threadIdx.x;
  int wv = tid >> 6, L = tid & 63;
  int lm = L & 15, lq = L >> 4;
  int g = blockIdx.x;                 // 1024 = 4 b * 128 y * 2 half
  int half = g & 1;
  int y = (g >> 1) & 127;
  int b = g >> 8;
  int pxg0 = half * 64;

  f4 acc[4];
#pragma unroll
  for (int i = 0; i < 4; ++i) acc[i] = (f4)0.f;

  for (int p = 0; p < 2; ++p) {
    const int tap0 = p ? 5 : 0;
    const int TAPS = p ? 4 : 5;
    __syncthreads();
    // ---- sampling phase: one thread per (px, tap)
    for (int u = tid; u < TAPS * 64; u += 256) {
      int px = u & 63;
      int tl = u >> 6;
      int k = tap0 + tl;
      int wg = pxg0 + px;
      int hw = (y << 7) + wg;
      int kr = k / 3;
      float oy = off[((b * 18 + 2 * k) << 14) + hw];
      float ox = off[((b * 18 + 2 * k + 1) << 14) + hw];
      float m = msk[((b * 9 + k) << 14) + hw];
      float py = (float)(y + kr - 1) + oy;
      float pxf = (float)(wg + (k - kr * 3) - 1) + ox;
      float fy = floorf(py), fx = floorf(pxf);
      float wy = py - fy, wx = pxf - fx;
      int y0 = (int)fy, x0 = (int)fx;
      int y1 = y0 + 1, x1 = x0 + 1;
      float vy0 = ((unsigned)y0 < 128u) ? 1.f : 0.f;
      float vy1 = ((unsigned)y1 < 128u) ? 1.f : 0.f;
      float vx0 = ((unsigned)x0 < 128u) ? 1.f : 0.f;
      float vx1 = ((unsigned)x1 < 128u) ? 1.f : 0.f;
      float ey = 1.f - wy, ex = 1.f - wx;
      float w00 = ey * ex * m * vy0 * vx0;
      float w01 = ey * wx * m * vy0 * vx1;
      float w10 = wy * ex * m * vy1 * vx0;
      float w11 = wy * wx * m * vy1 * vx1;
      int y0c = min(max(y0, 0), 127), y1c = min(max(y1, 0), 127);
      int x0c = min(max(x0, 0), 127), x1c = min(max(x1, 0), 127);
      const h8* p00 = (const h8*)(xT + (size_t)((((b << 7) + y0c) << 7) + x0c) * 64);
      const h8* p01 = (const h8*)(xT + (size_t)((((b << 7) + y0c) << 7) + x1c) * 64);
      const h8* p10 = (const h8*)(xT + (size_t)((((b << 7) + y1c) << 7) + x0c) * 64);
      const h8* p11 = (const h8*)(xT + (size_t)((((b << 7) + y1c) << 7) + x1c) * 64);
      _Float16* sp = &S[px * 328 + tl * 64];
#pragma unroll
      for (int cg = 0; cg < 8; ++cg) {
        h8 v00 = p00[cg], v01 = p01[cg], v10 = p10[cg], v11 = p11[cg];
        h8 o;
#pragma unroll
        for (int jj = 0; jj < 8; ++jj) {
          float s = fmaf(w11, (float)v11[jj],
                    fmaf(w10, (float)v10[jj],
                    fmaf(w01, (float)v01[jj], w00 * (float)v00[jj])));
          o[jj] = (_Float16)s;
        }
        *(h8*)(sp + cg * 8) = o;
      }
    }
    __syncthreads();
    // ---- MFMA phase: D[64 oc][64 px] += W[:, kslice] * S
    const int KS = 2 * TAPS;
    for (int ks = 0; ks < KS; ++ks) {
      int kg = tap0 * 64 + ks * 32;
      const _Float16* wp = wD + (size_t)lm * 576 + kg + lq * 8;
      h8 a0 = *(const h8*)(wp);
      h8 a1 = *(const h8*)(wp + 16 * 576);
      h8 a2 = *(const h8*)(wp + 32 * 576);
      h8 a3 = *(const h8*)(wp + 48 * 576);
      h8 bv = *(const h8*)(&S[(wv * 16 + lm) * 328 + ks * 32 + lq * 8]);
      acc[0] = __builtin_amdgcn_mfma_f32_16x16x32_f16(a0, bv, acc[0], 0, 0, 0);
      acc[1] = __builtin_amdgcn_mfma_f32_16x16x32_f16(a1, bv, acc[1], 0, 0, 0);
      acc[2] = __builtin_amdgcn_mfma_f32_16x16x32_f16(a2, bv, acc[2], 0, 0, 0);
      acc[3] = __builtin_amdgcn_mfma_f32_16x16x32_f16(a3, bv, acc[3], 0, 0, 0);
    }
  }
  // epilogue: bias + lrelu, fp32 NCHW; lane col = px (wave's 16-px strip)
  int px = pxg0 + wv * 16 + lm;
#pragma unroll
  for (int mt = 0; mt < 4; ++mt)
#pragma unroll
    for (int r = 0; r < 4; ++r) {
      int oc = mt * 16 + lq * 4 + r;
      float v = acc[mt][r] + bias[oc];
      v = (v >= 0.f) ? v : 0.1f * v;
      out[(((b << 6) + oc) << 14) + (y << 7) + px] = v;
    }
}

extern "C" void kernel_launch(void* const* d_in, const int* in_sizes, int n_in,
                              void* d_out, int out_size, void* d_ws, size_t ws_size,
                              hipStream_t stream) {
  const float* nbr   = (const float*)d_in[0];
  const float* refp  = (const float*)d_in[1];
  const float* w1    = (const float*)d_in[2];
  const float* b1    = (const float*)d_in[3];
  const float* w2    = (const float*)d_in[4];
  const float* b2    = (const float*)d_in[5];
  const float* w3    = (const float*)d_in[6];
  const float* b3    = (const float*)d_in[7];
  const float* w_off = (const float*)d_in[8];
  const float* b_off = (const float*)d_in[9];
  const float* w_dcn = (const float*)d_in[10];
  const float* b_dcn = (const float*)d_in[11];

  float* outp = (float*)d_out;
  float* feat = outp;                       // 4*64*16384
  float* offp = outp + 4194304;             // 4*18*16384
  float* mskp = outp + 4194304 + 1179648;   // 4*9*16384

  char* ws = (char*)d_ws;
  float* buf0 = (float*)ws;                 // 16 MB fp32 NCHW scratch
  // bufA (17.31 MB), time-shared: padded NHWC f16 (conv inputs) -> NHWC f16 (DCN input)
  char* bufA = ws + ((size_t)16u << 20);
  _Float16* nhwcX = (_Float16*)bufA;
  _Float16* xTf16 = (_Float16*)bufA;        // 8.4 MB, after conv_off done
  char* p = bufA + (size_t)17506304;
  _Float16* wF1 = (_Float16*)p;  p += (size_t)73728 * 2;   // conv1 [tap][4ch][64][32]
  _Float16* wF2 = (_Float16*)p;  p += (size_t)36864 * 2;
  _Float16* wF3 = (_Float16*)p;  p += (size_t)36864 * 2;
  _Float16* wFo = (_Float16*)p;  p += (size_t)18432 * 2;   // conv_off padded
  _Float16* wFd = (_Float16*)p;                            // dcn [oc][576]

  wprep_f16_kernel<<<dim3(288), 256, 0, stream>>>(w1, wF1, 4);
  wprep_f16_kernel<<<dim3(144), 256, 0, stream>>>(w2, wF2, 2);
  wprep_f16_kernel<<<dim3(144), 256, 0, stream>>>(w3, wF3, 2);
  wprep_off_kernel<<<dim3(72), 256, 0, stream>>>(w_off, wFo);
  wprep_dcn_kernel<<<dim3(144), 256, 0, stream>>>(w_dcn, wFd);

  // conv1: concat(nbr,ref) -> buf0
  prep_nhwc_f16_kernel<128, true><<<dim3(520), 256, 0, stream>>>(nbr, refp, (unsigned*)nhwcX);
  conv3x3_f16_kernel<128><<<dim3(512), 256, 0, stream>>>(nhwcX, wF1, b1, buf0);
  // conv2: buf0 -> feat (pong; overwritten by DCN)
  prep_nhwc_f16_kernel<64, false><<<dim3(520), 256, 0, stream>>>(buf0, nullptr, (unsigned*)nhwcX);
  conv3x3_f16_kernel<64><<<dim3(512), 256, 0, stream>>>(nhwcX, wF2, b2, feat);
  // conv3: feat -> buf0
  prep_nhwc_f16_kernel<64, false><<<dim3(520), 256, 0, stream>>>(feat, nullptr, (unsigned*)nhwcX);
  conv3x3_f16_kernel<64><<<dim3(512), 256, 0, stream>>>(nhwcX, wF3, b3, buf0);
  // conv_off: buf0 -> offset/mask (MFMA, fused tanh/sigmoid)
  prep_nhwc_f16_kernel<64, false><<<dim3(520), 256, 0, stream>>>(buf0, nullptr, (unsigned*)nhwcX);
  conv_off_f16_kernel<<<dim3(512), 256, 0, stream>>>(nhwcX, wFo, b_off, offp, mskp);
  // DCN: nbr -> NHWC f16, then sample->LDS->MFMA -> feat
  transpose_nhwc_f16_kernel<<<dim3(512), 256, 0, stream>>>(nbr, (unsigned*)xTf16);
  dcn_mfma_kernel<<<dim3(1024), 256, 0, stream>>>(xTf16, offp, mskp, wFd, b_dcn, feat);
}

// Round 7
// 278.069 us; speedup vs baseline: 4.0112x; 1.3008x over previous
//
#include <hip/hip_runtime.h>
#include <math.h>

// Problem constants: B=4, NF=64, H=W=128, K=9
// d_in order: nbr, ref, w1, b1, w2, b2, w3, b3, w_off, b_off, w_dcn, b_dcn
// d_out: feat [4,64,128,128] | offset [4,18,128,128] | mask [4,9,128,128]

typedef _Float16 h8 __attribute__((ext_vector_type(8)));  // 8 f16 (4 VGPRs)
typedef _Float16 h4 __attribute__((ext_vector_type(4)));  // 4 f16 (2 VGPRs)
typedef float f4 __attribute__((ext_vector_type(4)));     // 4 fp32 acc

// ---------------- merged f16 weight prep for all 5 weight tensors.
// conv weights: w[oc][ic][tap] -> wF[((tap*NCH+ch)*64+oc)*32+icw]
// off weights (pad 27->32): -> [((tap*2+ch)*32+oc)*32+icw]
// dcn weights: -> wD[oc*576 + tap*64 + c]
__global__ void wprep_all_kernel(
    const float* __restrict__ w1, const float* __restrict__ w2,
    const float* __restrict__ w3, const float* __restrict__ w_off,
    const float* __restrict__ w_dcn,
    _Float16* __restrict__ wF1, _Float16* __restrict__ wF2,
    _Float16* __restrict__ wF3, _Float16* __restrict__ wFo,
    _Float16* __restrict__ wFd) {
  int i = blockIdx.x * 256 + threadIdx.x;
  if (i < 73728) {                       // w1: NCH=4, IC=128
    int j = i;
    int icw = j & 31; int t1 = j >> 5; int oc = t1 & 63; int t2 = t1 >> 6;
    int ch = t2 & 3; int tap = t2 >> 2; int ic = ch * 32 + icw;
    wF1[j] = (_Float16)w1[(oc * 128 + ic) * 9 + tap];
  } else if (i < 110592) {               // w2: NCH=2
    int j = i - 73728;
    int icw = j & 31; int t1 = j >> 5; int oc = t1 & 63; int t2 = t1 >> 6;
    int ch = t2 & 1; int tap = t2 >> 1; int ic = ch * 32 + icw;
    wF2[j] = (_Float16)w2[(oc * 64 + ic) * 9 + tap];
  } else if (i < 147456) {               // w3: NCH=2
    int j = i - 110592;
    int icw = j & 31; int t1 = j >> 5; int oc = t1 & 63; int t2 = t1 >> 6;
    int ch = t2 & 1; int tap = t2 >> 1; int ic = ch * 32 + icw;
    wF3[j] = (_Float16)w3[(oc * 64 + ic) * 9 + tap];
  } else if (i < 165888) {               // w_off padded to 32 oc
    int j = i - 147456;
    int icw = j & 31; int t1 = j >> 5; int oc = t1 & 31; int t2 = t1 >> 5;
    int ch = t2 & 1; int tap = t2 >> 1; int ic = ch * 32 + icw;
    float v = (oc < 27) ? w_off[(oc * 64 + ic) * 9 + tap] : 0.f;
    wFo[j] = (_Float16)v;
  } else if (i < 202752) {               // w_dcn
    int j = i - 165888;
    int oc = j / 576; int r = j - oc * 576; int tap = r >> 6; int c = r & 63;
    wFd[j] = (_Float16)w_dcn[(oc * 64 + c) * 9 + tap];
  }
}

// ---------------- zero the pad borders of the three padded NHWC f16 buffers.
// A: CH=128, B/C: CH=64. 516 border px per (b, buffer).
__global__ void border_zero_kernel(_Float16* __restrict__ A, _Float16* __restrict__ B,
                                   _Float16* __restrict__ C) {
  int i = blockIdx.x * 256 + threadIdx.x;
  _Float16* dst; int CH; int j;
  if (i < 33024)      { dst = A; CH = 128; j = i; }
  else if (i < 49536) { dst = B; CH = 64;  j = i - 33024; }
  else if (i < 66048) { dst = C; CH = 64;  j = i - 49536; }
  else return;
  int chunks = CH >> 3;
  int cg = j % chunks; int t = j / chunks;   // t = b*516 + p
  int b = t / 516; int p = t - b * 516;
  int row, col;
  if (p < 130)      { row = 0;   col = p; }
  else if (p < 260) { row = 129; col = p - 130; }
  else if (p < 388) { row = 1 + (p - 260); col = 0; }
  else              { row = 1 + (p - 388); col = 129; }
  uint4 z; z.x = z.y = z.z = z.w = 0u;
  *(uint4*)(dst + ((size_t)(b * 130 + row) * 130 + col) * CH + cg * 8) = z;
}

// ---------------- fp32 NCHW -> zero-padded NHWC f16 [B][130][130][128] (conv1 concat input)
__global__ __launch_bounds__(256) void prep_nhwc128_kernel(
    const float* __restrict__ src0, const float* __restrict__ src1,
    unsigned* __restrict__ dst) {
  __shared__ float t[128 * 129];
  int bz = blockIdx.x;               // b*130 + py
  int b = bz / 130, py = bz - b * 130;
  int tid = threadIdx.x;
  bool interior = (py >= 1 && py <= 128);
  if (interior) {
    int gy = py - 1;
    for (int l = tid; l < 128 * 128; l += 256) {
      int c = l >> 7, gx = l & 127;
      const float* sp = (c >= 64) ? src1 : src0;
      int cl = c & 63;
      t[c * 129 + gx] = sp[(((size_t)b * 64 + cl) << 14) + (gy << 7) + gx];
    }
  }
  __syncthreads();
  for (int l = tid; l < 130 * 64; l += 256) {
    int px = l >> 6, c2 = l & 63;
    unsigned v = 0u;
    if (interior && px >= 1 && px <= 128) {
      int gx = px - 1;
      union { _Float16 h[2]; unsigned u; } pk;
      pk.h[0] = (_Float16)t[(2 * c2) * 129 + gx];
      pk.h[1] = (_Float16)t[(2 * c2 + 1) * 129 + gx];
      v = pk.u;
    }
    dst[(size_t)bz * (130 * 64) + l] = v;
  }
}

// ---------------- fp32 NCHW -> NHWC f16 (unpadded, for DCN): (B,64,128,128)->(B,128,128,64)
__global__ __launch_bounds__(256) void transpose_nhwc_f16_kernel(const float* __restrict__ in,
                                                                 unsigned* __restrict__ out) {
  __shared__ float t[64 * 129];
  int bz = blockIdx.x;            // b*128 + y
  int b = bz >> 7, y = bz & 127;
  int tid = threadIdx.x;
  for (int l = tid; l < 8192; l += 256) {
    int c = l >> 7, x = l & 127;
    t[c * 129 + x] = in[(((b << 6) + c) << 14) + (y << 7) + x];
  }
  __syncthreads();
  for (int l = tid; l < 4096; l += 256) {
    int x = l >> 5, c2 = l & 31;
    union { _Float16 h[2]; unsigned u; } pk;
    pk.h[0] = (_Float16)t[(2 * c2) * 129 + x];
    pk.h[1] = (_Float16)t[(2 * c2 + 1) * 129 + x];
    out[(size_t)bz * 4096 + (size_t)x * 32 + c2] = pk.u;
  }
}

// ---------------- f16 MFMA conv3x3 + bias + lrelu -> padded NHWC f16 [B][130][130][64].
// X: padded NHWC f16 [B][130][130][CH]; W: f16 slices [(tap*NCH+c)*64+oc][32].
// mfma_f32_16x16x32_f16 (lane L, lm=L&15, lq=L>>4):
//   a[j]=A[m=lm][k=lq*8+j]  b[j]=B[k=lq*8+j][n=lm]  d[r]=D[row=lq*4+r][col=lm]
template <int CH>
__global__ __launch_bounds__(256, 4) void conv3x3_f16_kernel(
    const _Float16* __restrict__ X, const _Float16* __restrict__ W,
    const float* __restrict__ bias, _Float16* __restrict__ outP) {
  constexpr int NCH = CH / 32;
  int tid = threadIdx.x;
  int wv = tid >> 6, L = tid & 63;
  int lm = L & 15, lq = L >> 4;
  int bid = blockIdx.x;                 // 512 = 8 xcd * 16 ystrip * 4 b
  int xcd = bid & 7, j = bid >> 3;
  int y = (xcd << 4) | (j & 15);
  int b = j >> 4;
  int px0 = wv * 32;

  f4 acc[4][2];
#pragma unroll
  for (int i = 0; i < 4; ++i)
#pragma unroll
    for (int n = 0; n < 2; ++n) acc[i][n] = (f4)0.f;

  for (int c = 0; c < NCH; ++c) {
#pragma unroll
    for (int tap = 0; tap < 9; ++tap) {
      const int dy = tap / 3 - 1, dx = tap % 3 - 1;
      const _Float16* xb = X + ((size_t)((b * 130 + (y + 1 + dy)) * 130) + (1 + dx) + px0) * CH
                             + c * 32 + lq * 8;
      h8 b0 = *(const h8*)(xb + lm * CH);
      h8 b1 = *(const h8*)(xb + (16 + lm) * CH);
      const _Float16* wp = W + (size_t)((tap * NCH + c) * 64) * 32 + lm * 32 + lq * 8;
      h8 a0 = *(const h8*)(wp);
      h8 a1 = *(const h8*)(wp + 512);
      h8 a2 = *(const h8*)(wp + 1024);
      h8 a3 = *(const h8*)(wp + 1536);
      acc[0][0] = __builtin_amdgcn_mfma_f32_16x16x32_f16(a0, b0, acc[0][0], 0, 0, 0);
      acc[1][0] = __builtin_amdgcn_mfma_f32_16x16x32_f16(a1, b0, acc[1][0], 0, 0, 0);
      acc[2][0] = __builtin_amdgcn_mfma_f32_16x16x32_f16(a2, b0, acc[2][0], 0, 0, 0);
      acc[3][0] = __builtin_amdgcn_mfma_f32_16x16x32_f16(a3, b0, acc[3][0], 0, 0, 0);
      acc[0][1] = __builtin_amdgcn_mfma_f32_16x16x32_f16(a0, b1, acc[0][1], 0, 0, 0);
      acc[1][1] = __builtin_amdgcn_mfma_f32_16x16x32_f16(a1, b1, acc[1][1], 0, 0, 0);
      acc[2][1] = __builtin_amdgcn_mfma_f32_16x16x32_f16(a2, b1, acc[2][1], 0, 0, 0);
      acc[3][1] = __builtin_amdgcn_mfma_f32_16x16x32_f16(a3, b1, acc[3][1], 0, 0, 0);
    }
  }
  // epilogue: bias + lrelu, pack 4 consecutive oc -> 8 B store, padded NHWC f16
  const size_t obase = ((size_t)(b * 130 + (y + 1)) * 130 + 1) * 64;
#pragma unroll
  for (int mt = 0; mt < 4; ++mt)
#pragma unroll
    for (int nt = 0; nt < 2; ++nt) {
      int px = px0 + nt * 16 + lm;
      h4 pk;
#pragma unroll
      for (int r = 0; r < 4; ++r) {
        int oc = mt * 16 + lq * 4 + r;
        float v = acc[mt][nt][r] + bias[oc];
        v = (v >= 0.f) ? v : 0.1f * v;
        pk[r] = (_Float16)v;
      }
      *(h4*)(outP + obase + (size_t)px * 64 + mt * 16 + lq * 4) = pk;
    }
}

// ---------------- f16 MFMA conv_off: 64 -> 27(pad 32), fused 15*tanh / sigmoid.
// W: [(tap*2+c)*32+oc][32] f16 (oc>=27 zero).
__global__ __launch_bounds__(256, 4) void conv_off_f16_kernel(
    const _Float16* __restrict__ X, const _Float16* __restrict__ W,
    const float* __restrict__ bias, float* __restrict__ off_out,
    float* __restrict__ mask_out) {
  int tid = threadIdx.x;
  int wv = tid >> 6, L = tid & 63;
  int lm = L & 15, lq = L >> 4;
  int bid = blockIdx.x;
  int xcd = bid & 7, j = bid >> 3;
  int y = (xcd << 4) | (j & 15);
  int b = j >> 4;
  int px0 = wv * 32;

  f4 acc[2][2];
#pragma unroll
  for (int i = 0; i < 2; ++i)
#pragma unroll
    for (int n = 0; n < 2; ++n) acc[i][n] = (f4)0.f;

  for (int c = 0; c < 2; ++c) {
#pragma unroll
    for (int tap = 0; tap < 9; ++tap) {
      const int dy = tap / 3 - 1, dx = tap % 3 - 1;
      const _Float16* xb = X + ((size_t)((b * 130 + (y + 1 + dy)) * 130) + (1 + dx) + px0) * 64
                             + c * 32 + lq * 8;
      h8 b0 = *(const h8*)(xb + lm * 64);
      h8 b1 = *(const h8*)(xb + (16 + lm) * 64);
      const _Float16* wp = W + (size_t)((tap * 2 + c) * 32 + lm) * 32 + lq * 8;
      h8 a0 = *(const h8*)(wp);
      h8 a1 = *(const h8*)(wp + 512);
      acc[0][0] = __builtin_amdgcn_mfma_f32_16x16x32_f16(a0, b0, acc[0][0], 0, 0, 0);
      acc[1][0] = __builtin_amdgcn_mfma_f32_16x16x32_f16(a1, b0, acc[1][0], 0, 0, 0);
      acc[0][1] = __builtin_amdgcn_mfma_f32_16x16x32_f16(a0, b1, acc[0][1], 0, 0, 0);
      acc[1][1] = __builtin_amdgcn_mfma_f32_16x16x32_f16(a1, b1, acc[1][1], 0, 0, 0);
    }
  }
#pragma unroll
  for (int mt = 0; mt < 2; ++mt)
#pragma unroll
    for (int nt = 0; nt < 2; ++nt) {
      int px = px0 + nt * 16 + lm;
      int hw = (y << 7) + px;
#pragma unroll
      for (int r = 0; r < 4; ++r) {
        int oc = mt * 16 + lq * 4 + r;
        if (oc < 18) {
          float v = acc[mt][nt][r] + bias[oc];
          off_out[((b * 18 + oc) << 14) + hw] = 15.f * tanhf(v);
        } else if (oc < 27) {
          float v = acc[mt][nt][r] + bias[oc];
          mask_out[((b * 9 + (oc - 18)) << 14) + hw] = 1.f / (1.f + expf(-v));
        }
      }
    }
}

// ---------------- DCN: bilinear sample (8 lanes/task) -> LDS -> MFMA + bias + lrelu.
// xT: NHWC f16 (B,128,128,64); wD: f16 [oc][tap*64+c]; block = 64 px (half row).
// Sampling lane map: t8=L>>3 (task in wave), c8=L&7 (channel octet) -> each corner
// load instr covers 8 contiguous 128 B pixel vectors (16 lines vs 64 scattered).
__global__ __launch_bounds__(256, 3) void dcn_mfma_kernel(
    const _Float16* __restrict__ xT, const float* __restrict__ off,
    const float* __restrict__ msk, const _Float16* __restrict__ wD,
    const float* __restrict__ bias, float* __restrict__ out) {
  __shared__ _Float16 S[64 * 328];
  int tid = threadIdx.x;
  int wv = tid >> 6, L = tid & 63;
  int lm = L & 15, lq = L >> 4;
  int t8 = L >> 3, c8 = L & 7;
  int g = blockIdx.x;                 // 1024 = 4 b * 128 y * 2 half
  int half = g & 1;
  int y = (g >> 1) & 127;
  int b = g >> 8;
  int pxg0 = half * 64;

  f4 acc[4];
#pragma unroll
  for (int i = 0; i < 4; ++i) acc[i] = (f4)0.f;

  for (int p = 0; p < 2; ++p) {
    const int tap0 = p ? 5 : 0;
    const int TAPS = p ? 4 : 5;
    __syncthreads();
    // ---- sampling: 8 lanes per (px, tap) task, 32 tasks per block-iteration
    const int NT = TAPS * 64;
    for (int u = wv * 8 + t8; u < NT; u += 32) {
      int px = u & 63;
      int tl = u >> 6;
      int k = tap0 + tl;
      int wg = pxg0 + px;
      int hw = (y << 7) + wg;
      int kr = k / 3;
      float oy = off[((b * 18 + 2 * k) << 14) + hw];
      float ox = off[((b * 18 + 2 * k + 1) << 14) + hw];
      float m = msk[((b * 9 + k) << 14) + hw];
      float py = (float)(y + kr - 1) + oy;
      float pxf = (float)(wg + (k - kr * 3) - 1) + ox;
      float fy = floorf(py), fx = floorf(pxf);
      float wy = py - fy, wx = pxf - fx;
      int y0 = (int)fy, x0 = (int)fx;
      int y1 = y0 + 1, x1 = x0 + 1;
      float vy0 = ((unsigned)y0 < 128u) ? 1.f : 0.f;
      float vy1 = ((unsigned)y1 < 128u) ? 1.f : 0.f;
      float vx0 = ((unsigned)x0 < 128u) ? 1.f : 0.f;
      float vx1 = ((unsigned)x1 < 128u) ? 1.f : 0.f;
      float ey = 1.f - wy, ex = 1.f - wx;
      float w00 = ey * ex * m * vy0 * vx0;
      float w01 = ey * wx * m * vy0 * vx1;
      float w10 = wy * ex * m * vy1 * vx0;
      float w11 = wy * wx * m * vy1 * vx1;
      int y0c = min(max(y0, 0), 127), y1c = min(max(y1, 0), 127);
      int x0c = min(max(x0, 0), 127), x1c = min(max(x1, 0), 127);
      int rb = b << 7;
      h8 v00 = *(const h8*)(xT + ((size_t)(((rb + y0c) << 7) + x0c) << 6) + c8 * 8);
      h8 v01 = *(const h8*)(xT + ((size_t)(((rb + y0c) << 7) + x1c) << 6) + c8 * 8);
      h8 v10 = *(const h8*)(xT + ((size_t)(((rb + y1c) << 7) + x0c) << 6) + c8 * 8);
      h8 v11 = *(const h8*)(xT + ((size_t)(((rb + y1c) << 7) + x1c) << 6) + c8 * 8);
      h8 o;
#pragma unroll
      for (int jj = 0; jj < 8; ++jj) {
        float s = fmaf(w11, (float)v11[jj],
                  fmaf(w10, (float)v10[jj],
                  fmaf(w01, (float)v01[jj], w00 * (float)v00[jj])));
        o[jj] = (_Float16)s;
      }
      *(h8*)&S[px * 328 + tl * 64 + c8 * 8] = o;
    }
    __syncthreads();
    // ---- MFMA phase: D[64 oc][64 px] += W[:, kslice] * S
    const int KS = 2 * TAPS;
    for (int ks = 0; ks < KS; ++ks) {
      int kg = tap0 * 64 + ks * 32;
      const _Float16* wp = wD + (size_t)lm * 576 + kg + lq * 8;
      h8 a0 = *(const h8*)(wp);
      h8 a1 = *(const h8*)(wp + 16 * 576);
      h8 a2 = *(const h8*)(wp + 32 * 576);
      h8 a3 = *(const h8*)(wp + 48 * 576);
      h8 bv = *(const h8*)(&S[(wv * 16 + lm) * 328 + ks * 32 + lq * 8]);
      acc[0] = __builtin_amdgcn_mfma_f32_16x16x32_f16(a0, bv, acc[0], 0, 0, 0);
      acc[1] = __builtin_amdgcn_mfma_f32_16x16x32_f16(a1, bv, acc[1], 0, 0, 0);
      acc[2] = __builtin_amdgcn_mfma_f32_16x16x32_f16(a2, bv, acc[2], 0, 0, 0);
      acc[3] = __builtin_amdgcn_mfma_f32_16x16x32_f16(a3, bv, acc[3], 0, 0, 0);
    }
  }
  // epilogue: bias + lrelu, fp32 NCHW
  int px = pxg0 + wv * 16 + lm;
#pragma unroll
  for (int mt = 0; mt < 4; ++mt)
#pragma unroll
    for (int r = 0; r < 4; ++r) {
      int oc = mt * 16 + lq * 4 + r;
      float v = acc[mt][r] + bias[oc];
      v = (v >= 0.f) ? v : 0.1f * v;
      out[(((b << 6) + oc) << 14) + (y << 7) + px] = v;
    }
}

extern "C" void kernel_launch(void* const* d_in, const int* in_sizes, int n_in,
                              void* d_out, int out_size, void* d_ws, size_t ws_size,
                              hipStream_t stream) {
  const float* nbr   = (const float*)d_in[0];
  const float* refp  = (const float*)d_in[1];
  const float* w1    = (const float*)d_in[2];
  const float* b1    = (const float*)d_in[3];
  const float* w2    = (const float*)d_in[4];
  const float* b2    = (const float*)d_in[5];
  const float* w3    = (const float*)d_in[6];
  const float* b3    = (const float*)d_in[7];
  const float* w_off = (const float*)d_in[8];
  const float* b_off = (const float*)d_in[9];
  const float* w_dcn = (const float*)d_in[10];
  const float* b_dcn = (const float*)d_in[11];

  float* outp = (float*)d_out;
  float* feat = outp;                       // 4*64*16384
  float* offp = outp + 4194304;             // 4*18*16384
  float* mskp = outp + 4194304 + 1179648;   // 4*9*16384

  char* ws = (char*)d_ws;
  // A128: padded NHWC f16 [4][130][130][128] (conv1 input); DCN xT f16 aliases here later.
  _Float16* A128 = (_Float16*)ws;                        // 17,305,600 B
  _Float16* xTf16 = (_Float16*)ws;                       // 8,388,608 B (after conv1 dead)
  _Float16* B64 = (_Float16*)(ws + (size_t)17305600);    // 8,652,800 B
  _Float16* C64 = (_Float16*)(ws + (size_t)17305600 + 8652800);
  char* p = ws + (size_t)17305600 + 8652800 + 8652800;
  _Float16* wF1 = (_Float16*)p;  p += (size_t)73728 * 2;
  _Float16* wF2 = (_Float16*)p;  p += (size_t)36864 * 2;
  _Float16* wF3 = (_Float16*)p;  p += (size_t)36864 * 2;
  _Float16* wFo = (_Float16*)p;  p += (size_t)18432 * 2;
  _Float16* wFd = (_Float16*)p;

  wprep_all_kernel<<<dim3(792), 256, 0, stream>>>(w1, w2, w3, w_off, w_dcn,
                                                  wF1, wF2, wF3, wFo, wFd);
  border_zero_kernel<<<dim3(258), 256, 0, stream>>>(A128, B64, C64);

  // conv1: concat(nbr,ref) f16-NHWC -> B64 (padded NHWC f16 direct)
  prep_nhwc128_kernel<<<dim3(520), 256, 0, stream>>>(nbr, refp, (unsigned*)A128);
  conv3x3_f16_kernel<128><<<dim3(512), 256, 0, stream>>>(A128, wF1, b1, B64);
  // conv2: B64 -> C64 ; conv3: C64 -> B64
  conv3x3_f16_kernel<64><<<dim3(512), 256, 0, stream>>>(B64, wF2, b2, C64);
  conv3x3_f16_kernel<64><<<dim3(512), 256, 0, stream>>>(C64, wF3, b3, B64);
  // conv_off: B64 -> offset/mask (fused tanh/sigmoid)
  conv_off_f16_kernel<<<dim3(512), 256, 0, stream>>>(B64, wFo, b_off, offp, mskp);
  // DCN: nbr -> NHWC f16 (aliases dead A128), then sample->LDS->MFMA -> feat
  transpose_nhwc_f16_kernel<<<dim3(512), 256, 0, stream>>>(nbr, (unsigned*)xTf16);
  dcn_mfma_kernel<<<dim3(1024), 256, 0, stream>>>(xTf16, offp, mskp, wFd, b_dcn, feat);
}

// Round 8
// 252.844 us; speedup vs baseline: 4.4113x; 1.0998x over previous
//
#include <hip/hip_runtime.h>
#include <math.h>

// Problem constants: B=4, NF=64, H=W=128, K=9
// d_in order: nbr, ref, w1, b1, w2, b2, w3, b3, w_off, b_off, w_dcn, b_dcn
// d_out: feat [4,64,128,128] | offset [4,18,128,128] | mask [4,9,128,128]

typedef _Float16 h8 __attribute__((ext_vector_type(8)));  // 8 f16 (4 VGPRs)
typedef _Float16 h4 __attribute__((ext_vector_type(4)));  // 4 f16 (2 VGPRs)
typedef _Float16 h2 __attribute__((ext_vector_type(2)));  // packed f16 pair
typedef float f4 __attribute__((ext_vector_type(4)));     // 4 fp32 acc

// ================ merged setup: weight prep + border zero + input prep ================
// roles by blockIdx: [0,792) wprep, [792,1050) border zero, [1050,3098) NCHW->padded NHWC f16
__global__ __launch_bounds__(256) void setup_kernel(
    const float* __restrict__ nbr, const float* __restrict__ refp,
    const float* __restrict__ w1, const float* __restrict__ w2,
    const float* __restrict__ w3, const float* __restrict__ w_off,
    const float* __restrict__ w_dcn,
    _Float16* __restrict__ X1, _Float16* __restrict__ X2,
    _Float16* __restrict__ B64, _Float16* __restrict__ C64,
    _Float16* __restrict__ wF1, _Float16* __restrict__ wF2,
    _Float16* __restrict__ wF3, _Float16* __restrict__ wFo,
    _Float16* __restrict__ wFd) {
  __shared__ float t[64 * 65];
  int bid = blockIdx.x;
  int tid = threadIdx.x;
  if (bid < 792) {
    // ---- weight prep (f16)
    int i = bid * 256 + tid;
    if (i < 73728) {                       // w1: global chunk 0..3 (128 IC)
      int j = i;
      int icw = j & 31; int t1 = j >> 5; int oc = t1 & 63; int t2 = t1 >> 6;
      int ch = t2 & 3; int tap = t2 >> 2; int ic = ch * 32 + icw;
      wF1[j] = (_Float16)w1[(oc * 128 + ic) * 9 + tap];
    } else if (i < 110592) {               // w2
      int j = i - 73728;
      int icw = j & 31; int t1 = j >> 5; int oc = t1 & 63; int t2 = t1 >> 6;
      int ch = t2 & 1; int tap = t2 >> 1; int ic = ch * 32 + icw;
      wF2[j] = (_Float16)w2[(oc * 64 + ic) * 9 + tap];
    } else if (i < 147456) {               // w3
      int j = i - 110592;
      int icw = j & 31; int t1 = j >> 5; int oc = t1 & 63; int t2 = t1 >> 6;
      int ch = t2 & 1; int tap = t2 >> 1; int ic = ch * 32 + icw;
      wF3[j] = (_Float16)w3[(oc * 64 + ic) * 9 + tap];
    } else if (i < 165888) {               // w_off padded to 32 oc
      int j = i - 147456;
      int icw = j & 31; int t1 = j >> 5; int oc = t1 & 31; int t2 = t1 >> 5;
      int ch = t2 & 1; int tap = t2 >> 1; int ic = ch * 32 + icw;
      float v = (oc < 27) ? w_off[(oc * 64 + ic) * 9 + tap] : 0.f;
      wFo[j] = (_Float16)v;
    } else if (i < 202752) {               // w_dcn -> [oc][tap*64+c]
      int j = i - 165888;
      int oc = j / 576; int r = j - oc * 576; int tap = r >> 6; int c = r & 63;
      wFd[j] = (_Float16)w_dcn[(oc * 64 + c) * 9 + tap];
    }
    return;
  }
  if (bid < 1050) {
    // ---- zero pad borders of X1, X2, B64, C64 (all CH=64)
    int i = (bid - 792) * 256 + tid;       // 66048 = 4 buf * 4 b * 516 px * 8 chunks
    int bufi = i / 16512;
    int j = i - bufi * 16512;
    int b = j / 4128;
    int r = j - b * 4128;
    int p = r >> 3; int cg = r & 7;
    int row, col;
    if (p < 130)      { row = 0;   col = p; }
    else if (p < 260) { row = 129; col = p - 130; }
    else if (p < 388) { row = 1 + (p - 260); col = 0; }
    else              { row = 1 + (p - 388); col = 129; }
    _Float16* dst = (bufi == 0) ? X1 : (bufi == 1) ? X2 : (bufi == 2) ? B64 : C64;
    uint4 z; z.x = z.y = z.z = z.w = 0u;
    *(uint4*)(dst + ((size_t)(b * 130 + row) * 130 + col) * 64 + cg * 8) = z;
    return;
  }
  // ---- input prep: fp32 NCHW -> padded NHWC f16 (64-px half-rows)
  int j = bid - 1050;                      // 2048 = 2 src * 4 b * 128 y * 2 half
  int half = j & 1;
  int y = (j >> 1) & 127;
  int b = (j >> 8) & 3;
  int src = j >> 10;
  const float* sp = src ? refp : nbr;
  _Float16* dst = src ? X2 : X1;
  for (int l = tid; l < 64 * 64; l += 256) {
    int c = l >> 6, gx = l & 63;
    t[c * 65 + gx] = sp[(((size_t)b * 64 + c) << 14) + (y << 7) + half * 64 + gx];
  }
  __syncthreads();
  unsigned* dstU = (unsigned*)dst;
  for (int l = tid; l < 64 * 32; l += 256) {
    int pxl = l >> 5, c2 = l & 31;
    union { _Float16 h[2]; unsigned u; } pk;
    pk.h[0] = (_Float16)t[(2 * c2) * 65 + pxl];
    pk.h[1] = (_Float16)t[(2 * c2 + 1) * 65 + pxl];
    dstU[((size_t)(b * 130 + y + 1) * 130 + 1 + half * 64 + pxl) * 32 + c2] = pk.u;
  }
}

// ================ f16 MFMA conv3x3 + bias + lrelu -> padded NHWC f16 ================
// All inputs are padded NHWC f16 [B][130][130][64]; conv1 reads two (concat via SPLIT).
// W: f16 slices [(tap*NCH+c)*64+oc][32].
// mfma_f32_16x16x32_f16 (lane L, lm=L&15, lq=L>>4):
//   a[j]=A[m=lm][k=lq*8+j]  b[j]=B[k=lq*8+j][n=lm]  d[r]=D[row=lq*4+r][col=lm]
template <int NCH, bool SPLIT>
__global__ __launch_bounds__(256, 4) void conv3x3_f16_kernel(
    const _Float16* __restrict__ X1, const _Float16* __restrict__ X2,
    const _Float16* __restrict__ W, const float* __restrict__ bias,
    _Float16* __restrict__ outP) {
  int tid = threadIdx.x;
  int wv = tid >> 6, L = tid & 63;
  int lm = L & 15, lq = L >> 4;
  int bid = blockIdx.x;                 // 512 = 8 xcd * 16 ystrip * 4 b
  int xcd = bid & 7, j = bid >> 3;
  int y = (xcd << 4) | (j & 15);
  int b = j >> 4;
  int px0 = wv * 32;

  f4 acc[4][2];
#pragma unroll
  for (int i = 0; i < 4; ++i)
#pragma unroll
    for (int n = 0; n < 2; ++n) acc[i][n] = (f4)0.f;

  for (int c = 0; c < NCH; ++c) {
    const _Float16* src = (SPLIT && c >= 2) ? X2 : X1;
    int cl = SPLIT ? (c & 1) : c;
#pragma unroll
    for (int tap = 0; tap < 9; ++tap) {
      const int dy = tap / 3 - 1, dx = tap % 3 - 1;
      const _Float16* xb = src + ((size_t)((b * 130 + (y + 1 + dy)) * 130) + (1 + dx) + px0) * 64
                               + cl * 32 + lq * 8;
      h8 b0 = *(const h8*)(xb + lm * 64);
      h8 b1 = *(const h8*)(xb + (16 + lm) * 64);
      const _Float16* wp = W + (size_t)((tap * NCH + c) * 64) * 32 + lm * 32 + lq * 8;
      h8 a0 = *(const h8*)(wp);
      h8 a1 = *(const h8*)(wp + 512);
      h8 a2 = *(const h8*)(wp + 1024);
      h8 a3 = *(const h8*)(wp + 1536);
      acc[0][0] = __builtin_amdgcn_mfma_f32_16x16x32_f16(a0, b0, acc[0][0], 0, 0, 0);
      acc[1][0] = __builtin_amdgcn_mfma_f32_16x16x32_f16(a1, b0, acc[1][0], 0, 0, 0);
      acc[2][0] = __builtin_amdgcn_mfma_f32_16x16x32_f16(a2, b0, acc[2][0], 0, 0, 0);
      acc[3][0] = __builtin_amdgcn_mfma_f32_16x16x32_f16(a3, b0, acc[3][0], 0, 0, 0);
      acc[0][1] = __builtin_amdgcn_mfma_f32_16x16x32_f16(a0, b1, acc[0][1], 0, 0, 0);
      acc[1][1] = __builtin_amdgcn_mfma_f32_16x16x32_f16(a1, b1, acc[1][1], 0, 0, 0);
      acc[2][1] = __builtin_amdgcn_mfma_f32_16x16x32_f16(a2, b1, acc[2][1], 0, 0, 0);
      acc[3][1] = __builtin_amdgcn_mfma_f32_16x16x32_f16(a3, b1, acc[3][1], 0, 0, 0);
    }
  }
  // epilogue: bias + lrelu, pack 4 consecutive oc -> 8 B store, padded NHWC f16
  const size_t obase = ((size_t)(b * 130 + (y + 1)) * 130 + 1) * 64;
#pragma unroll
  for (int mt = 0; mt < 4; ++mt)
#pragma unroll
    for (int nt = 0; nt < 2; ++nt) {
      int px = px0 + nt * 16 + lm;
      h4 pk;
#pragma unroll
      for (int r = 0; r < 4; ++r) {
        int oc = mt * 16 + lq * 4 + r;
        float v = acc[mt][nt][r] + bias[oc];
        v = (v >= 0.f) ? v : 0.1f * v;
        pk[r] = (_Float16)v;
      }
      *(h4*)(outP + obase + (size_t)px * 64 + mt * 16 + lq * 4) = pk;
    }
}

// ================ f16 MFMA conv_off: 64 -> 27(pad 32), fused 15*tanh / sigmoid ========
__global__ __launch_bounds__(256, 4) void conv_off_f16_kernel(
    const _Float16* __restrict__ X, const _Float16* __restrict__ W,
    const float* __restrict__ bias, float* __restrict__ off_out,
    float* __restrict__ mask_out) {
  int tid = threadIdx.x;
  int wv = tid >> 6, L = tid & 63;
  int lm = L & 15, lq = L >> 4;
  int bid = blockIdx.x;
  int xcd = bid & 7, j = bid >> 3;
  int y = (xcd << 4) | (j & 15);
  int b = j >> 4;
  int px0 = wv * 32;

  f4 acc[2][2];
#pragma unroll
  for (int i = 0; i < 2; ++i)
#pragma unroll
    for (int n = 0; n < 2; ++n) acc[i][n] = (f4)0.f;

  for (int c = 0; c < 2; ++c) {
#pragma unroll
    for (int tap = 0; tap < 9; ++tap) {
      const int dy = tap / 3 - 1, dx = tap % 3 - 1;
      const _Float16* xb = X + ((size_t)((b * 130 + (y + 1 + dy)) * 130) + (1 + dx) + px0) * 64
                             + c * 32 + lq * 8;
      h8 b0 = *(const h8*)(xb + lm * 64);
      h8 b1 = *(const h8*)(xb + (16 + lm) * 64);
      const _Float16* wp = W + (size_t)((tap * 2 + c) * 32 + lm) * 32 + lq * 8;
      h8 a0 = *(const h8*)(wp);
      h8 a1 = *(const h8*)(wp + 512);
      acc[0][0] = __builtin_amdgcn_mfma_f32_16x16x32_f16(a0, b0, acc[0][0], 0, 0, 0);
      acc[1][0] = __builtin_amdgcn_mfma_f32_16x16x32_f16(a1, b0, acc[1][0], 0, 0, 0);
      acc[0][1] = __builtin_amdgcn_mfma_f32_16x16x32_f16(a0, b1, acc[0][1], 0, 0, 0);
      acc[1][1] = __builtin_amdgcn_mfma_f32_16x16x32_f16(a1, b1, acc[1][1], 0, 0, 0);
    }
  }
#pragma unroll
  for (int mt = 0; mt < 2; ++mt)
#pragma unroll
    for (int nt = 0; nt < 2; ++nt) {
      int px = px0 + nt * 16 + lm;
      int hw = (y << 7) + px;
#pragma unroll
      for (int r = 0; r < 4; ++r) {
        int oc = mt * 16 + lq * 4 + r;
        if (oc < 18) {
          float v = acc[mt][nt][r] + bias[oc];
          off_out[((b * 18 + oc) << 14) + hw] = 15.f * tanhf(v);
        } else if (oc < 27) {
          float v = acc[mt][nt][r] + bias[oc];
          mask_out[((b * 9 + (oc - 18)) << 14) + hw] = 1.f / (1.f + expf(-v));
        }
      }
    }
}

// ================ DCN: sample (8 lanes/task, packed-f16 blend) -> LDS -> MFMA ==========
// Xp: PADDED NHWC f16 [B][130][130][64] (= X1, the prepped nbr); wD: f16 [oc][tap*64+c].
// Block = 32 px (quarter row), 128 threads (2 waves). LDS S[32][328].
__global__ __launch_bounds__(128, 4) void dcn_mfma_kernel(
    const _Float16* __restrict__ Xp, const float* __restrict__ off,
    const float* __restrict__ msk, const _Float16* __restrict__ wD,
    const float* __restrict__ bias, float* __restrict__ out) {
  __shared__ _Float16 S[32 * 328];
  int tid = threadIdx.x;
  int wv = tid >> 6, L = tid & 63;
  int lm = L & 15, lq = L >> 4;
  int t8 = L >> 3, c8 = L & 7;
  int g = blockIdx.x;                 // 2048 = 4 b * 128 y * 4 quarter
  int q = g & 3;
  int y = (g >> 2) & 127;
  int b = g >> 9;
  int pxq0 = q * 32;

  f4 acc[4];
#pragma unroll
  for (int i = 0; i < 4; ++i) acc[i] = (f4)0.f;

  for (int p = 0; p < 2; ++p) {
    const int tap0 = p ? 5 : 0;
    const int TAPS = p ? 4 : 5;
    __syncthreads();
    // ---- sampling: 8 lanes per (px, tap) task; 16 task-groups per iteration
    const int NT = TAPS * 32;
    for (int u = wv * 8 + t8; u < NT; u += 16) {
      int px = u & 31;
      int tl = u >> 5;
      int k = tap0 + tl;
      int wg = pxq0 + px;
      int hw = (y << 7) + wg;
      int kr = k / 3;
      float oy = off[((b * 18 + 2 * k) << 14) + hw];
      float ox = off[((b * 18 + 2 * k + 1) << 14) + hw];
      float m = msk[((b * 9 + k) << 14) + hw];
      float py = (float)(y + kr - 1) + oy;
      float pxf = (float)(wg + (k - kr * 3) - 1) + ox;
      float fy = floorf(py), fx = floorf(pxf);
      float wy = py - fy, wx = pxf - fx;
      int y0 = (int)fy, x0 = (int)fx;
      int y1 = y0 + 1, x1 = x0 + 1;
      float vy0 = ((unsigned)y0 < 128u) ? 1.f : 0.f;
      float vy1 = ((unsigned)y1 < 128u) ? 1.f : 0.f;
      float vx0 = ((unsigned)x0 < 128u) ? 1.f : 0.f;
      float vx1 = ((unsigned)x1 < 128u) ? 1.f : 0.f;
      float ey = 1.f - wy, ex = 1.f - wx;
      _Float16 w00 = (_Float16)(ey * ex * m * vy0 * vx0);
      _Float16 w01 = (_Float16)(ey * wx * m * vy0 * vx1);
      _Float16 w10 = (_Float16)(wy * ex * m * vy1 * vx0);
      _Float16 w11 = (_Float16)(wy * wx * m * vy1 * vx1);
      h2 W00 = {w00, w00}, W01 = {w01, w01}, W10 = {w10, w10}, W11 = {w11, w11};
      int y0c = min(max(y0, 0), 127) + 1, y1c = min(max(y1, 0), 127) + 1;
      int x0c = min(max(x0, 0), 127) + 1, x1c = min(max(x1, 0), 127) + 1;
      int rb = b * 130;
      h8 v00 = *(const h8*)(Xp + ((size_t)((rb + y0c) * 130 + x0c) << 6) + c8 * 8);
      h8 v01 = *(const h8*)(Xp + ((size_t)((rb + y0c) * 130 + x1c) << 6) + c8 * 8);
      h8 v10 = *(const h8*)(Xp + ((size_t)((rb + y1c) * 130 + x0c) << 6) + c8 * 8);
      h8 v11 = *(const h8*)(Xp + ((size_t)((rb + y1c) * 130 + x1c) << 6) + c8 * 8);
      h8 o;
#pragma unroll
      for (int j2 = 0; j2 < 4; ++j2) {
        h2 a = {v00[2 * j2], v00[2 * j2 + 1]};
        h2 bb = {v01[2 * j2], v01[2 * j2 + 1]};
        h2 cc = {v10[2 * j2], v10[2 * j2 + 1]};
        h2 dd = {v11[2 * j2], v11[2 * j2 + 1]};
        h2 r = a * W00;
        r += bb * W01;
        r += cc * W10;
        r += dd * W11;
        o[2 * j2] = r[0];
        o[2 * j2 + 1] = r[1];
      }
      *(h8*)&S[px * 328 + tl * 64 + c8 * 8] = o;
    }
    __syncthreads();
    // ---- MFMA: D[64 oc][32 px] += W[:, kslice] * S (wave covers 16 px)
    const int KS = 2 * TAPS;
    for (int ks = 0; ks < KS; ++ks) {
      int kg = tap0 * 64 + ks * 32;
      const _Float16* wp = wD + (size_t)lm * 576 + kg + lq * 8;
      h8 a0 = *(const h8*)(wp);
      h8 a1 = *(const h8*)(wp + 16 * 576);
      h8 a2 = *(const h8*)(wp + 32 * 576);
      h8 a3 = *(const h8*)(wp + 48 * 576);
      h8 bv = *(const h8*)(&S[(wv * 16 + lm) * 328 + ks * 32 + lq * 8]);
      acc[0] = __builtin_amdgcn_mfma_f32_16x16x32_f16(a0, bv, acc[0], 0, 0, 0);
      acc[1] = __builtin_amdgcn_mfma_f32_16x16x32_f16(a1, bv, acc[1], 0, 0, 0);
      acc[2] = __builtin_amdgcn_mfma_f32_16x16x32_f16(a2, bv, acc[2], 0, 0, 0);
      acc[3] = __builtin_amdgcn_mfma_f32_16x16x32_f16(a3, bv, acc[3], 0, 0, 0);
    }
  }
  // epilogue: bias + lrelu, fp32 NCHW
  int px = pxq0 + wv * 16 + lm;
#pragma unroll
  for (int mt = 0; mt < 4; ++mt)
#pragma unroll
    for (int r = 0; r < 4; ++r) {
      int oc = mt * 16 + lq * 4 + r;
      float v = acc[mt][r] + bias[oc];
      v = (v >= 0.f) ? v : 0.1f * v;
      out[(((b << 6) + oc) << 14) + (y << 7) + px] = v;
    }
}

extern "C" void kernel_launch(void* const* d_in, const int* in_sizes, int n_in,
                              void* d_out, int out_size, void* d_ws, size_t ws_size,
                              hipStream_t stream) {
  const float* nbr   = (const float*)d_in[0];
  const float* refp  = (const float*)d_in[1];
  const float* w1    = (const float*)d_in[2];
  const float* b1    = (const float*)d_in[3];
  const float* w2    = (const float*)d_in[4];
  const float* b2    = (const float*)d_in[5];
  const float* w3    = (const float*)d_in[6];
  const float* b3    = (const float*)d_in[7];
  const float* w_off = (const float*)d_in[8];
  const float* b_off = (const float*)d_in[9];
  const float* w_dcn = (const float*)d_in[10];
  const float* b_dcn = (const float*)d_in[11];

  float* outp = (float*)d_out;
  float* feat = outp;                       // 4*64*16384
  float* offp = outp + 4194304;             // 4*18*16384
  float* mskp = outp + 4194304 + 1179648;   // 4*9*16384

  // ws layout: four padded NHWC f16 buffers [4][130][130][64] + f16 weights (~33.4 MiB)
  char* ws = (char*)d_ws;
  const size_t PB = 8652800;                // bytes per padded buffer
  _Float16* X1  = (_Float16*)ws;            // nbr padded (conv1 in + DCN sample src)
  _Float16* X2  = (_Float16*)(ws + PB);     // ref padded
  _Float16* B64 = (_Float16*)(ws + 2 * PB); // conv1 out / conv3 out
  _Float16* C64 = (_Float16*)(ws + 3 * PB); // conv2 out
  char* p = ws + 4 * PB;
  _Float16* wF1 = (_Float16*)p;  p += (size_t)73728 * 2;
  _Float16* wF2 = (_Float16*)p;  p += (size_t)36864 * 2;
  _Float16* wF3 = (_Float16*)p;  p += (size_t)36864 * 2;
  _Float16* wFo = (_Float16*)p;  p += (size_t)18432 * 2;
  _Float16* wFd = (_Float16*)p;

  // 6 dispatches total
  setup_kernel<<<dim3(3098), 256, 0, stream>>>(nbr, refp, w1, w2, w3, w_off, w_dcn,
                                               X1, X2, B64, C64, wF1, wF2, wF3, wFo, wFd);
  conv3x3_f16_kernel<4, true><<<dim3(512), 256, 0, stream>>>(X1, X2, wF1, b1, B64);
  conv3x3_f16_kernel<2, false><<<dim3(512), 256, 0, stream>>>(B64, B64, wF2, b2, C64);
  conv3x3_f16_kernel<2, false><<<dim3(512), 256, 0, stream>>>(C64, C64, wF3, b3, B64);
  conv_off_f16_kernel<<<dim3(512), 256, 0, stream>>>(B64, wFo, b_off, offp, mskp);
  dcn_mfma_kernel<<<dim3(2048), 128, 0, stream>>>(X1, offp, mskp, wFd, b_dcn, feat);
}